// Round 1
// 2420.702 us; speedup vs baseline: 1.1629x; 1.1629x over previous
//
#include <hip/hip_runtime.h>
#include <hip/hip_bf16.h>

#define PLANE (1 << 20)   // 1024*1024

typedef __attribute__((ext_vector_type(8))) short bf16x8;
typedef __attribute__((ext_vector_type(4))) float f32x4;

struct SegOff { long o[6]; };

union U4 { ushort u[4]; unsigned long long v; };

__device__ __forceinline__ ushort bf16bits(float v) {
    union { __hip_bfloat16 b; ushort u; } c;
    c.b = __float2bfloat16(v);
    return c.u;
}

__device__ __forceinline__ void split2(float v, ushort& hi, ushort& lo) {
    union { __hip_bfloat16 b; ushort u; } c;
    __hip_bfloat16 h = __float2bfloat16(v);
    c.b = h; hi = c.u;
    c.b = __float2bfloat16(v - __bfloat162float(h));
    lo = c.u;
}

__device__ __forceinline__ void gload16(const ushort* g, ushort* l) {
    __builtin_amdgcn_global_load_lds(
        (const __attribute__((address_space(1))) unsigned int*)g,
        (__attribute__((address_space(3))) unsigned int*)l, 16, 0, 0);
}

// ---------------------------------------------------------------------------
// B = (A - A^H) * scale
// ---------------------------------------------------------------------------
__global__ __launch_bounds__(256) void build_skew_k(
    const float* __restrict__ Ure, const float* __restrict__ Uim,
    float* __restrict__ Bre, float* __restrict__ Bim, float scale)
{
    int idx = blockIdx.x * 256 + threadIdx.x;
    int ij  = idx & (PLANE - 1);
    int i   = ij >> 10, j = ij & 1023;
    int t   = (idx & ~(PLANE - 1)) | (j << 10) | i;
    Bre[idx] = (Ure[idx] - Ure[t]) * scale;
    Bim[idx] = (Uim[idx] + Uim[t]) * scale;
}

// T = I + B * inv
__global__ __launch_bounds__(256) void init_T_k(
    const float* __restrict__ Bre, const float* __restrict__ Bim,
    float* __restrict__ Tre, float* __restrict__ Tim, float inv)
{
    int idx = blockIdx.x * 256 + threadIdx.x;
    int ij  = idx & (PLANE - 1);
    int i   = ij >> 10, j = ij & 1023;
    Tre[idx] = Bre[idx] * inv + ((i == j) ? 1.0f : 0.0f);
    Tim[idx] = Bim[idx] * inv;
}

// ---------------------------------------------------------------------------
// Split-K reduction: C = (C + P0 + P1 + P2) * scale  [+ I on real diagonal]
// C is 4 contiguous fp32 planes [pack(re/im)][inner k][1024][1024].
// PB holds 3 partial copies of the same 4-plane layout.
// ---------------------------------------------------------------------------
__global__ __launch_bounds__(256) void reduce_k(
    float* __restrict__ C, const float* __restrict__ PB, float scale, int addI)
{
    long e = ((long)blockIdx.x * 256 + threadIdx.x) * 4;   // 4*PLANE floats total
    float4 v = *(float4*)(C + e);
    const float4 a = *(const float4*)(PB + e);
    const float4 b = *(const float4*)(PB + 4L * PLANE + e);
    const float4 c = *(const float4*)(PB + 8L * PLANE + e);
    v.x = (v.x + a.x + b.x + c.x) * scale;
    v.y = (v.y + a.y + b.y + c.y) * scale;
    v.z = (v.z + a.z + b.z + c.z) * scale;
    v.w = (v.w + a.w + b.w + c.w) * scale;
    if (addI) {
        long p = e >> 20;                 // plane index 0..3 (0,1 = real part)
        if (p < 2) {
            int ij = (int)(e & (PLANE - 1));
            int i = ij >> 10, j = ij & 1023;
            if (i >= j && i < j + 4) ((float*)&v)[i - j] += 1.0f;
        }
    }
    *(float4*)(C + e) = v;
}

// ---------------------------------------------------------------------------
// Pack A (expm, 6 segments): Ab[4 z][1024][6144]
//   z = pack*2 + k
//   pack0: [Arh, Arh, Arl, -Aih, -Aih, -Ail]
//   pack1: [Aih, Aih, Ail,  Arh,  Arh,  Arl]
// ---------------------------------------------------------------------------
__global__ __launch_bounds__(256) void pack_A6_k(
    const float* __restrict__ Sre, const float* __restrict__ Sim,
    ushort* __restrict__ Ab)
{
    int idx = blockIdx.x * 256 + threadIdx.x;     // 524288 threads
    int k   = idx >> 18;
    int m   = (idx >> 8) & 1023;
    int c4  = (idx & 255) * 4;
    const float4 vr = *(const float4*)(Sre + (size_t)k * PLANE + (size_t)m * 1024 + c4);
    const float4 vi = *(const float4*)(Sim + (size_t)k * PLANE + (size_t)m * 1024 + c4);
    U4 rh, rl, ih, il, nih, nil;
    split2(vr.x, rh.u[0], rl.u[0]); split2(vr.y, rh.u[1], rl.u[1]);
    split2(vr.z, rh.u[2], rl.u[2]); split2(vr.w, rh.u[3], rl.u[3]);
    split2(vi.x, ih.u[0], il.u[0]); split2(vi.y, ih.u[1], il.u[1]);
    split2(vi.z, ih.u[2], il.u[2]); split2(vi.w, ih.u[3], il.u[3]);
    #pragma unroll
    for (int i = 0; i < 4; ++i) { nih.u[i] = ih.u[i] ^ 0x8000; nil.u[i] = il.u[i] ^ 0x8000; }

    long b0 = (long)k * 1024 * 6144 + (long)m * 6144;
    long b1 = (long)(2 + k) * 1024 * 6144 + (long)m * 6144;
    *(unsigned long long*)&Ab[b0 + 0*1024 + c4] = rh.v;
    *(unsigned long long*)&Ab[b0 + 1*1024 + c4] = rh.v;
    *(unsigned long long*)&Ab[b0 + 2*1024 + c4] = rl.v;
    *(unsigned long long*)&Ab[b0 + 3*1024 + c4] = nih.v;
    *(unsigned long long*)&Ab[b0 + 4*1024 + c4] = nih.v;
    *(unsigned long long*)&Ab[b0 + 5*1024 + c4] = nil.v;
    *(unsigned long long*)&Ab[b1 + 0*1024 + c4] = ih.v;
    *(unsigned long long*)&Ab[b1 + 1*1024 + c4] = ih.v;
    *(unsigned long long*)&Ab[b1 + 2*1024 + c4] = il.v;
    *(unsigned long long*)&Ab[b1 + 3*1024 + c4] = rh.v;
    *(unsigned long long*)&Ab[b1 + 4*1024 + c4] = rh.v;
    *(unsigned long long*)&Ab[b1 + 5*1024 + c4] = rl.v;
}

// ---------------------------------------------------------------------------
// Pack A (apply, 4 segments): Ab[4 z][1024][4096]
//   pack0: [Urh, Url, -Uih, -Uil]    pack1: [Uih, Uil, Urh, Url]
// ---------------------------------------------------------------------------
__global__ __launch_bounds__(256) void pack_A4_k(
    const float* __restrict__ Sre, const float* __restrict__ Sim,
    ushort* __restrict__ Ab)
{
    int idx = blockIdx.x * 256 + threadIdx.x;
    int k   = idx >> 18;
    int m   = (idx >> 8) & 1023;
    int c4  = (idx & 255) * 4;
    const float4 vr = *(const float4*)(Sre + (size_t)k * PLANE + (size_t)m * 1024 + c4);
    const float4 vi = *(const float4*)(Sim + (size_t)k * PLANE + (size_t)m * 1024 + c4);
    U4 rh, rl, ih, il, nih, nil;
    split2(vr.x, rh.u[0], rl.u[0]); split2(vr.y, rh.u[1], rl.u[1]);
    split2(vr.z, rh.u[2], rl.u[2]); split2(vr.w, rh.u[3], rl.u[3]);
    split2(vi.x, ih.u[0], il.u[0]); split2(vi.y, ih.u[1], il.u[1]);
    split2(vi.z, ih.u[2], il.u[2]); split2(vi.w, ih.u[3], il.u[3]);
    #pragma unroll
    for (int i = 0; i < 4; ++i) { nih.u[i] = ih.u[i] ^ 0x8000; nil.u[i] = il.u[i] ^ 0x8000; }

    long b0 = (long)k * 1024 * 4096 + (long)m * 4096;
    long b1 = (long)(2 + k) * 1024 * 4096 + (long)m * 4096;
    *(unsigned long long*)&Ab[b0 + 0*1024 + c4] = rh.v;
    *(unsigned long long*)&Ab[b0 + 1*1024 + c4] = rl.v;
    *(unsigned long long*)&Ab[b0 + 2*1024 + c4] = nih.v;
    *(unsigned long long*)&Ab[b0 + 3*1024 + c4] = nil.v;
    *(unsigned long long*)&Ab[b1 + 0*1024 + c4] = ih.v;
    *(unsigned long long*)&Ab[b1 + 1*1024 + c4] = il.v;
    *(unsigned long long*)&Ab[b1 + 2*1024 + c4] = rh.v;
    *(unsigned long long*)&Ab[b1 + 3*1024 + c4] = rl.v;
}

// ---------------------------------------------------------------------------
// Transpose + split T -> Tt[4 kind][2 k][1024][1024]  (kind: rh, rl, ih, il)
// ---------------------------------------------------------------------------
__global__ __launch_bounds__(256) void pack_BT6_k(
    const float* __restrict__ Sre, const float* __restrict__ Sim,
    ushort* __restrict__ Tt)
{
    __shared__ float Lre[64][65];
    __shared__ float Lim[64][65];
    int k = blockIdx.z, r0 = blockIdx.y * 64, c0 = blockIdx.x * 64;
    int tid = threadIdx.x;
    const float* br = Sre + (size_t)k * PLANE;
    const float* bi = Sim + (size_t)k * PLANE;
    #pragma unroll
    for (int p = 0; p < 16; ++p) {
        int idx = p * 256 + tid, r = idx >> 6, c = idx & 63;
        Lre[r][c] = br[(size_t)(r0 + r) * 1024 + c0 + c];
        Lim[r][c] = bi[(size_t)(r0 + r) * 1024 + c0 + c];
    }
    __syncthreads();
    #pragma unroll
    for (int p = 0; p < 4; ++p) {
        int s = p * 256 + tid, oc = s >> 4, r4 = (s & 15) * 4;
        U4 rh, rl, ih, il;
        #pragma unroll
        for (int i = 0; i < 4; ++i) {
            split2(Lre[r4 + i][oc], rh.u[i], rl.u[i]);
            split2(Lim[r4 + i][oc], ih.u[i], il.u[i]);
        }
        size_t dst = (size_t)k * PLANE + (size_t)(c0 + oc) * 1024 + r0 + r4;
        *(unsigned long long*)&Tt[0L * 2 * PLANE + dst] = rh.v;
        *(unsigned long long*)&Tt[1L * 2 * PLANE + dst] = rl.v;
        *(unsigned long long*)&Tt[2L * 2 * PLANE + dst] = ih.v;
        *(unsigned long long*)&Tt[3L * 2 * PLANE + dst] = il.v;
    }
}

// ---------------------------------------------------------------------------
// Transpose + convert x -> xT[2 kind][4 plane][4096][1024] (plain bf16)
// ---------------------------------------------------------------------------
__global__ __launch_bounds__(256) void pack_xT_k(
    const float* __restrict__ xre, const float* __restrict__ xim,
    ushort* __restrict__ xT)
{
    __shared__ float Lre[64][65];
    __shared__ float Lim[64][65];
    int pl = blockIdx.z, t0 = blockIdx.y * 64, c0 = blockIdx.x * 64;
    int tid = threadIdx.x;
    const float* br = xre + ((size_t)pl << 22);
    const float* bi = xim + ((size_t)pl << 22);
    #pragma unroll
    for (int p = 0; p < 16; ++p) {
        int idx = p * 256 + tid, r = idx >> 6, c = idx & 63;
        Lre[r][c] = br[(size_t)(t0 + r) * 4096 + c0 + c];
        Lim[r][c] = bi[(size_t)(t0 + r) * 4096 + c0 + c];
    }
    __syncthreads();
    #pragma unroll
    for (int p = 0; p < 4; ++p) {
        int s = p * 256 + tid, oc = s >> 4, r4 = (s & 15) * 4;
        U4 re4, im4;
        #pragma unroll
        for (int i = 0; i < 4; ++i) {
            re4.u[i] = bf16bits(Lre[r4 + i][oc]);
            im4.u[i] = bf16bits(Lim[r4 + i][oc]);
        }
        size_t dst = ((size_t)pl << 22) + (size_t)(c0 + oc) * 1024 + t0 + r4;
        *(unsigned long long*)&xT[dst] = re4.v;
        *(unsigned long long*)&xT[(4L << 22) + dst] = im4.v;
    }
}

// ---------------------------------------------------------------------------
// bf16 MFMA GEMM: C[z] = scale * A[z] . B(segmented) [+ I]
// A row-major [1024][Ktot], B segments are transposed planes [n][1024]
// 128x128 tile, 256 threads (4 waves, each 64x64 via 4x4 of 16x16x32 MFMA)
// Split-K: gridDim.z = (2*zHalf) * nChunks; each chunk covers kLen columns.
// Chunk 0 writes the C buffers (with scale/+I); chunks >=1 write raw partial
// sums to PB[chunk-1][pack][inner][1024][1024] (reduced by reduce_k).
// ---------------------------------------------------------------------------
__global__ __launch_bounds__(256, 2) void gemm_bt_k(
    const ushort* __restrict__ Ab, long aPackStride, long aInnerStride, int aInnerDiv, int aLd,
    const ushort* __restrict__ Bb, SegOff segs, long bZStride,
    float* __restrict__ CreB, float* __restrict__ CimB, long cZStride, int cLd,
    int kLen, int zHalf, float scale, int addI,
    float* __restrict__ PB)
{
    __shared__ ushort As[128 * 32];
    __shared__ ushort Bs[128 * 32];

    const int zTot  = 2 * zHalf;
    const int chunk = blockIdx.z / zTot;
    const int zb    = blockIdx.z % zTot;
    const int pack = zb / zHalf, inner = zb % zHalf;
    const ushort* A = Ab + (long)pack * aPackStride + (long)(inner / aInnerDiv) * aInnerStride;
    float* C = (chunk == 0)
        ? ((pack ? CimB : CreB) + (long)inner * cZStride)
        : (PB + (long)(chunk - 1) * 4 * PLANE + (long)pack * 2 * PLANE + (long)inner * PLANE);

    const int tid = threadIdx.x;
    const int lane = tid & 63, wave = tid >> 6;
    const int m0 = blockIdx.y * 128, n0 = blockIdx.x * 128;
    const int wm = (wave >> 1) * 64, wn = (wave & 1) * 64;
    const int l15 = lane & 15, quad = lane >> 4;

    f32x4 acc[4][4] = {};

    const int kStart = chunk * kLen, kEnd = kStart + kLen;
    for (int kb = kStart; kb < kEnd; kb += 32) {
        const ushort* Bp = Bb + segs.o[kb >> 10] + (long)inner * bZStride + (kb & 1023);
        #pragma unroll
        for (int q = 0; q < 2; ++q) {
            int c = q * 256 + wave * 64 + lane;
            gload16(A + (long)(m0 + (c >> 2)) * aLd + kb + (c & 3) * 8,
                    &As[(q * 256 + wave * 64) * 8]);
            gload16(Bp + (long)(n0 + (c >> 2)) * 1024 + (c & 3) * 8,
                    &Bs[(q * 256 + wave * 64) * 8]);
        }
        __syncthreads();
        bf16x8 af[4], bfr[4];
        #pragma unroll
        for (int i = 0; i < 4; ++i)
            af[i] = *(const bf16x8*)&As[(wm + i * 16 + l15) * 32 + quad * 8];
        #pragma unroll
        for (int j = 0; j < 4; ++j)
            bfr[j] = *(const bf16x8*)&Bs[(wn + j * 16 + l15) * 32 + quad * 8];
        #pragma unroll
        for (int i = 0; i < 4; ++i)
            #pragma unroll
            for (int j = 0; j < 4; ++j)
                acc[i][j] = __builtin_amdgcn_mfma_f32_16x16x32_bf16(af[i], bfr[j], acc[i][j], 0, 0, 0);
        __syncthreads();
    }

    #pragma unroll
    for (int i = 0; i < 4; ++i) {
        int row0 = m0 + wm + i * 16 + quad * 4;
        #pragma unroll
        for (int j = 0; j < 4; ++j) {
            int col = n0 + wn + j * 16 + l15;
            #pragma unroll
            for (int r = 0; r < 4; ++r) {
                float v = acc[i][j][r] * scale;
                if (addI && chunk == 0 && pack == 0 && (row0 + r) == col) v += 1.0f;
                C[(long)(row0 + r) * cLd + col] = v;
            }
        }
    }
}

// ---------------------------------------------------------------------------
extern "C" void kernel_launch(void* const* d_in, const int* in_sizes, int n_in,
                              void* d_out, int out_size, void* d_ws, size_t ws_size,
                              hipStream_t stream)
{
    const float* x_re = (const float*)d_in[0];
    const float* x_im = (const float*)d_in[1];
    const float* U_re = (const float*)d_in[2];
    const float* U_im = (const float*)d_in[3];
    float* out = (float*)d_out;

    // ws layout (160 MiB):
    //   [0,48M):   6 fp32 planes [2][1024][1024]: Tre,Tim,Rre,Rim,BSre,BSim
    //   [48,96M):  Askew bf16 [4][1024][6144]  (later reused as A_apply [4][1024][4096])
    //              -> during SQUARINGS this region is dead: split-K partials live here
    //   [96,144M): At bf16 [4][1024][6144]   } reused as xT [2][4][4096][1024] (64 MiB)
    //              -> during HORNER this region is dead: split-K partials live here
    //   [144,160M): Tt bf16 [4][2][1024][1024]
    float* fp = (float*)d_ws;
    float* Tre = fp + 0L * 2 * PLANE;
    float* Tim = fp + 1L * 2 * PLANE;
    float* Rre = fp + 2L * 2 * PLANE;
    float* Rim = fp + 3L * 2 * PLANE;
    float* BSre = fp + 4L * 2 * PLANE;
    float* BSim = fp + 5L * 2 * PLANE;
    ushort* Askew = (ushort*)((char*)d_ws + (48L << 20));
    ushort* At    = (ushort*)((char*)d_ws + (96L << 20));
    ushort* Tt    = (ushort*)((char*)d_ws + (144L << 20));
    ushort* Aap   = Askew;
    ushort* xT    = At;
    float* Phorner = (float*)At;      // 48 MiB free during Horner
    float* Psquare = (float*)Askew;   // 48 MiB free during squarings

    dim3 blk(256);

    const float scaleB = 1.0f / 512.0f;   // ||skew|| ~128 -> ||B|| ~0.25, s=9
    build_skew_k<<<dim3(2 * PLANE / 256), blk, 0, stream>>>(U_re, U_im, BSre, BSim, scaleB);
    init_T_k<<<dim3(2 * PLANE / 256), blk, 0, stream>>>(BSre, BSim, Tre, Tim, 1.0f / 8.0f);
    pack_A6_k<<<dim3(2048), blk, 0, stream>>>(BSre, BSim, Askew);

    SegOff se;
    se.o[0] = 0L;           se.o[1] = 2L * PLANE;  se.o[2] = 0L;
    se.o[3] = 4L * PLANE;   se.o[4] = 6L * PLANE;  se.o[5] = 4L * PLANE;

    dim3 ge(8, 8, 16);                 // 4 z * 4 K-chunks = 1024 blocks (4/CU)
    dim3 gr(PLANE / 256);              // reduce: 4*PLANE floats / (256*4)
    // Horner: T <- I + (B @ T)/j
    for (int j = 7; j >= 1; --j) {
        pack_BT6_k<<<dim3(16, 16, 2), blk, 0, stream>>>(Tre, Tim, Tt);
        gemm_bt_k<<<ge, blk, 0, stream>>>(Askew, 2L * 1024 * 6144, 1024L * 6144, 1, 6144,
                                          Tt, se, (long)PLANE,
                                          Rre, Rim, (long)PLANE, 1024,
                                          1536, 2, 1.0f, 0, Phorner);
        reduce_k<<<gr, blk, 0, stream>>>(Rre, Phorner, 1.0f / (float)j, 1);
        float* t;
        t = Tre; Tre = Rre; Rre = t;
        t = Tim; Tim = Rim; Rim = t;
    }
    // 9 squarings: T <- T @ T
    for (int s = 0; s < 9; ++s) {
        pack_A6_k<<<dim3(2048), blk, 0, stream>>>(Tre, Tim, At);
        pack_BT6_k<<<dim3(16, 16, 2), blk, 0, stream>>>(Tre, Tim, Tt);
        gemm_bt_k<<<ge, blk, 0, stream>>>(At, 2L * 1024 * 6144, 1024L * 6144, 1, 6144,
                                          Tt, se, (long)PLANE,
                                          Rre, Rim, (long)PLANE, 1024,
                                          1536, 2, 1.0f, 0, Psquare);
        reduce_k<<<gr, blk, 0, stream>>>(Rre, Psquare, 1.0f, 0);
        float* t;
        t = Tre; Tre = Rre; Rre = t;
        t = Tim; Tim = Rim; Rim = t;
    }

    // Apply: out[k,b1] = U[k] @ X[k,b1]
    pack_A4_k<<<dim3(2048), blk, 0, stream>>>(Tre, Tim, Aap);
    pack_xT_k<<<dim3(64, 16, 4), blk, 0, stream>>>(x_re, x_im, xT);

    SegOff sa;
    sa.o[0] = 0L;        sa.o[1] = 0L;
    sa.o[2] = 4L << 22;  sa.o[3] = 4L << 22;
    sa.o[4] = 0L;        sa.o[5] = 0L;

    gemm_bt_k<<<dim3(32, 8, 8), blk, 0, stream>>>(Aap, 2L * 1024 * 4096, 1024L * 4096, 2, 4096,
                                                  xT, sa, 1L << 22,
                                                  out, out + (1L << 24), 1L << 22, 4096,
                                                  4096, 4, 1.0f, 0, (float*)nullptr);
}

// Round 2
// 2245.920 us; speedup vs baseline: 1.2534x; 1.0778x over previous
//
#include <hip/hip_runtime.h>
#include <hip/hip_bf16.h>

#define PLANE (1 << 20)   // 1024*1024

typedef __attribute__((ext_vector_type(8))) short bf16x8;
typedef __attribute__((ext_vector_type(4))) float f32x4;

struct SegOff { long o[6]; };

union U4 { ushort u[4]; unsigned long long v; };

__device__ __forceinline__ ushort bf16bits(float v) {
    union { __hip_bfloat16 b; ushort u; } c;
    c.b = __float2bfloat16(v);
    return c.u;
}

__device__ __forceinline__ void split2(float v, ushort& hi, ushort& lo) {
    union { __hip_bfloat16 b; ushort u; } c;
    __hip_bfloat16 h = __float2bfloat16(v);
    c.b = h; hi = c.u;
    c.b = __float2bfloat16(v - __bfloat162float(h));
    lo = c.u;
}

__device__ __forceinline__ void gload16(const ushort* g, ushort* l) {
    __builtin_amdgcn_global_load_lds(
        (const __attribute__((address_space(1))) unsigned int*)g,
        (__attribute__((address_space(3))) unsigned int*)l, 16, 0, 0);
}

// ---------------------------------------------------------------------------
// B = (A - A^H) * scale
// ---------------------------------------------------------------------------
__global__ __launch_bounds__(256) void build_skew_k(
    const float* __restrict__ Ure, const float* __restrict__ Uim,
    float* __restrict__ Bre, float* __restrict__ Bim, float scale)
{
    int idx = blockIdx.x * 256 + threadIdx.x;
    int ij  = idx & (PLANE - 1);
    int i   = ij >> 10, j = ij & 1023;
    int t   = (idx & ~(PLANE - 1)) | (j << 10) | i;
    Bre[idx] = (Ure[idx] - Ure[t]) * scale;
    Bim[idx] = (Uim[idx] + Uim[t]) * scale;
}

// T = I + B * inv
__global__ __launch_bounds__(256) void init_T_k(
    const float* __restrict__ Bre, const float* __restrict__ Bim,
    float* __restrict__ Tre, float* __restrict__ Tim, float inv)
{
    int idx = blockIdx.x * 256 + threadIdx.x;
    int ij  = idx & (PLANE - 1);
    int i   = ij >> 10, j = ij & 1023;
    Tre[idx] = Bre[idx] * inv + ((i == j) ? 1.0f : 0.0f);
    Tim[idx] = Bim[idx] * inv;
}

// ---------------------------------------------------------------------------
// Split-K reduction: C = (C + P0 + P1 + P2) * scale  [+ I on real diagonal]
// ---------------------------------------------------------------------------
__global__ __launch_bounds__(256) void reduce_k(
    float* __restrict__ C, const float* __restrict__ PB, float scale, int addI)
{
    long e = ((long)blockIdx.x * 256 + threadIdx.x) * 4;   // 4*PLANE floats total
    float4 v = *(float4*)(C + e);
    const float4 a = *(const float4*)(PB + e);
    const float4 b = *(const float4*)(PB + 4L * PLANE + e);
    const float4 c = *(const float4*)(PB + 8L * PLANE + e);
    v.x = (v.x + a.x + b.x + c.x) * scale;
    v.y = (v.y + a.y + b.y + c.y) * scale;
    v.z = (v.z + a.z + b.z + c.z) * scale;
    v.w = (v.w + a.w + b.w + c.w) * scale;
    if (addI) {
        long p = e >> 20;                 // plane index 0..3 (0,1 = real part)
        if (p < 2) {
            int ij = (int)(e & (PLANE - 1));
            int i = ij >> 10, j = ij & 1023;
            if (i >= j && i < j + 4) ((float*)&v)[i - j] += 1.0f;
        }
    }
    *(float4*)(C + e) = v;
}

// ---------------------------------------------------------------------------
// Pack A (expm, 6 segments): Ab[4 z][1024][6144]
// ---------------------------------------------------------------------------
__global__ __launch_bounds__(256) void pack_A6_k(
    const float* __restrict__ Sre, const float* __restrict__ Sim,
    ushort* __restrict__ Ab)
{
    int idx = blockIdx.x * 256 + threadIdx.x;     // 524288 threads
    int k   = idx >> 18;
    int m   = (idx >> 8) & 1023;
    int c4  = (idx & 255) * 4;
    const float4 vr = *(const float4*)(Sre + (size_t)k * PLANE + (size_t)m * 1024 + c4);
    const float4 vi = *(const float4*)(Sim + (size_t)k * PLANE + (size_t)m * 1024 + c4);
    U4 rh, rl, ih, il, nih, nil;
    split2(vr.x, rh.u[0], rl.u[0]); split2(vr.y, rh.u[1], rl.u[1]);
    split2(vr.z, rh.u[2], rl.u[2]); split2(vr.w, rh.u[3], rl.u[3]);
    split2(vi.x, ih.u[0], il.u[0]); split2(vi.y, ih.u[1], il.u[1]);
    split2(vi.z, ih.u[2], il.u[2]); split2(vi.w, ih.u[3], il.u[3]);
    #pragma unroll
    for (int i = 0; i < 4; ++i) { nih.u[i] = ih.u[i] ^ 0x8000; nil.u[i] = il.u[i] ^ 0x8000; }

    long b0 = (long)k * 1024 * 6144 + (long)m * 6144;
    long b1 = (long)(2 + k) * 1024 * 6144 + (long)m * 6144;
    *(unsigned long long*)&Ab[b0 + 0*1024 + c4] = rh.v;
    *(unsigned long long*)&Ab[b0 + 1*1024 + c4] = rh.v;
    *(unsigned long long*)&Ab[b0 + 2*1024 + c4] = rl.v;
    *(unsigned long long*)&Ab[b0 + 3*1024 + c4] = nih.v;
    *(unsigned long long*)&Ab[b0 + 4*1024 + c4] = nih.v;
    *(unsigned long long*)&Ab[b0 + 5*1024 + c4] = nil.v;
    *(unsigned long long*)&Ab[b1 + 0*1024 + c4] = ih.v;
    *(unsigned long long*)&Ab[b1 + 1*1024 + c4] = ih.v;
    *(unsigned long long*)&Ab[b1 + 2*1024 + c4] = il.v;
    *(unsigned long long*)&Ab[b1 + 3*1024 + c4] = rh.v;
    *(unsigned long long*)&Ab[b1 + 4*1024 + c4] = rh.v;
    *(unsigned long long*)&Ab[b1 + 5*1024 + c4] = rl.v;
}

// ---------------------------------------------------------------------------
// Pack A (apply, 4 segments): Ab[4 z][1024][4096]
// ---------------------------------------------------------------------------
__global__ __launch_bounds__(256) void pack_A4_k(
    const float* __restrict__ Sre, const float* __restrict__ Sim,
    ushort* __restrict__ Ab)
{
    int idx = blockIdx.x * 256 + threadIdx.x;
    int k   = idx >> 18;
    int m   = (idx >> 8) & 1023;
    int c4  = (idx & 255) * 4;
    const float4 vr = *(const float4*)(Sre + (size_t)k * PLANE + (size_t)m * 1024 + c4);
    const float4 vi = *(const float4*)(Sim + (size_t)k * PLANE + (size_t)m * 1024 + c4);
    U4 rh, rl, ih, il, nih, nil;
    split2(vr.x, rh.u[0], rl.u[0]); split2(vr.y, rh.u[1], rl.u[1]);
    split2(vr.z, rh.u[2], rl.u[2]); split2(vr.w, rh.u[3], rl.u[3]);
    split2(vi.x, ih.u[0], il.u[0]); split2(vi.y, ih.u[1], il.u[1]);
    split2(vi.z, ih.u[2], il.u[2]); split2(vi.w, ih.u[3], il.u[3]);
    #pragma unroll
    for (int i = 0; i < 4; ++i) { nih.u[i] = ih.u[i] ^ 0x8000; nil.u[i] = il.u[i] ^ 0x8000; }

    long b0 = (long)k * 1024 * 4096 + (long)m * 4096;
    long b1 = (long)(2 + k) * 1024 * 4096 + (long)m * 4096;
    *(unsigned long long*)&Ab[b0 + 0*1024 + c4] = rh.v;
    *(unsigned long long*)&Ab[b0 + 1*1024 + c4] = rl.v;
    *(unsigned long long*)&Ab[b0 + 2*1024 + c4] = nih.v;
    *(unsigned long long*)&Ab[b0 + 3*1024 + c4] = nil.v;
    *(unsigned long long*)&Ab[b1 + 0*1024 + c4] = ih.v;
    *(unsigned long long*)&Ab[b1 + 1*1024 + c4] = il.v;
    *(unsigned long long*)&Ab[b1 + 2*1024 + c4] = rh.v;
    *(unsigned long long*)&Ab[b1 + 3*1024 + c4] = rl.v;
}

// ---------------------------------------------------------------------------
// Transpose + split T -> Tt[4 kind][2 k][1024][1024]  (kind: rh, rl, ih, il)
// ---------------------------------------------------------------------------
__global__ __launch_bounds__(256) void pack_BT6_k(
    const float* __restrict__ Sre, const float* __restrict__ Sim,
    ushort* __restrict__ Tt)
{
    __shared__ float Lre[64][65];
    __shared__ float Lim[64][65];
    int k = blockIdx.z, r0 = blockIdx.y * 64, c0 = blockIdx.x * 64;
    int tid = threadIdx.x;
    const float* br = Sre + (size_t)k * PLANE;
    const float* bi = Sim + (size_t)k * PLANE;
    #pragma unroll
    for (int p = 0; p < 16; ++p) {
        int idx = p * 256 + tid, r = idx >> 6, c = idx & 63;
        Lre[r][c] = br[(size_t)(r0 + r) * 1024 + c0 + c];
        Lim[r][c] = bi[(size_t)(r0 + r) * 1024 + c0 + c];
    }
    __syncthreads();
    #pragma unroll
    for (int p = 0; p < 4; ++p) {
        int s = p * 256 + tid, oc = s >> 4, r4 = (s & 15) * 4;
        U4 rh, rl, ih, il;
        #pragma unroll
        for (int i = 0; i < 4; ++i) {
            split2(Lre[r4 + i][oc], rh.u[i], rl.u[i]);
            split2(Lim[r4 + i][oc], ih.u[i], il.u[i]);
        }
        size_t dst = (size_t)k * PLANE + (size_t)(c0 + oc) * 1024 + r0 + r4;
        *(unsigned long long*)&Tt[0L * 2 * PLANE + dst] = rh.v;
        *(unsigned long long*)&Tt[1L * 2 * PLANE + dst] = rl.v;
        *(unsigned long long*)&Tt[2L * 2 * PLANE + dst] = ih.v;
        *(unsigned long long*)&Tt[3L * 2 * PLANE + dst] = il.v;
    }
}

// ---------------------------------------------------------------------------
// Transpose + convert x -> xT[2 kind][4 plane][4096][1024] (plain bf16)
// ---------------------------------------------------------------------------
__global__ __launch_bounds__(256) void pack_xT_k(
    const float* __restrict__ xre, const float* __restrict__ xim,
    ushort* __restrict__ xT)
{
    __shared__ float Lre[64][65];
    __shared__ float Lim[64][65];
    int pl = blockIdx.z, t0 = blockIdx.y * 64, c0 = blockIdx.x * 64;
    int tid = threadIdx.x;
    const float* br = xre + ((size_t)pl << 22);
    const float* bi = xim + ((size_t)pl << 22);
    #pragma unroll
    for (int p = 0; p < 16; ++p) {
        int idx = p * 256 + tid, r = idx >> 6, c = idx & 63;
        Lre[r][c] = br[(size_t)(t0 + r) * 4096 + c0 + c];
        Lim[r][c] = bi[(size_t)(t0 + r) * 4096 + c0 + c];
    }
    __syncthreads();
    #pragma unroll
    for (int p = 0; p < 4; ++p) {
        int s = p * 256 + tid, oc = s >> 4, r4 = (s & 15) * 4;
        U4 re4, im4;
        #pragma unroll
        for (int i = 0; i < 4; ++i) {
            re4.u[i] = bf16bits(Lre[r4 + i][oc]);
            im4.u[i] = bf16bits(Lim[r4 + i][oc]);
        }
        size_t dst = ((size_t)pl << 22) + (size_t)(c0 + oc) * 1024 + t0 + r4;
        *(unsigned long long*)&xT[dst] = re4.v;
        *(unsigned long long*)&xT[(4L << 22) + dst] = im4.v;
    }
}

// ---------------------------------------------------------------------------
// 256x256-tile 8-phase bf16 MFMA GEMM (T2 swizzle + T3/T4 counted vmcnt + T5).
// 512 threads = 8 waves (2M x 4N), per-wave output 128x64, BK=64.
// LDS 128 KiB: 2 buffers x (A 256x64 + B 256x64) bf16.
// Staging depth 2: tile t+2 issued after phase-4 barrier of tile t (all waves'
// ds_reads of buf[t&1] provably serviced); vmcnt(8) at tile top completes
// exactly tile t while tile t+1's 8 loads stay in flight (never drains to 0).
// st_16x32 swizzle: byte ^= ((byte>>9)&1)<<5, applied as inverse-swizzled
// global source (linear global_load_lds dest) + swizzled ds_read address.
// ---------------------------------------------------------------------------
__global__ __launch_bounds__(512, 2) void gemm256_k(
    const ushort* __restrict__ Ab, long aPackStride, long aInnerStride, int aInnerDiv, int aLd,
    const ushort* __restrict__ Bb, SegOff segs, long bZStride,
    float* __restrict__ CreB, float* __restrict__ CimB, long cZStride, int cLd,
    int kLen, int zHalf, float scale, int addI,
    float* __restrict__ PB)
{
    __shared__ ushort lds[2][32768];   // per buf: A [0,16384), B [16384,32768) ushorts

    const int zTot  = 2 * zHalf;
    const int chunk = blockIdx.z / zTot;
    const int zb    = blockIdx.z % zTot;
    const int pack  = zb / zHalf, inner = zb % zHalf;
    const ushort* A = Ab + (long)pack * aPackStride + (long)(inner / aInnerDiv) * aInnerStride;
    float* C = (chunk == 0)
        ? ((pack ? CimB : CreB) + (long)inner * cZStride)
        : (PB + (long)(chunk - 1) * 4 * PLANE + (long)pack * 2 * PLANE + (long)inner * PLANE);

    const int tid  = threadIdx.x;
    const int lane = tid & 63, wave = tid >> 6;
    const int wr = wave >> 2, wc = wave & 3;       // 2M x 4N wave grid
    const int l15 = lane & 15, quad = lane >> 4;
    const int m0 = blockIdx.y * 256, n0 = blockIdx.x * 256;

    // staging thread-constants (inverse-swizzled global source)
    const int srow  = lane >> 3;                                        // 0..7
    const int scolE = ((((lane & 7) * 16) ^ (((lane >> 5) & 1) << 5)) >> 1);  // elem col 0..63
    // frag-read bases (ushort units), pre-swizzled; phase offsets have bit5==0
    const int xorv  = ((l15 >> 2) & 1) << 5;                            // byte xor
    const int abase = ((((wr * 128 + l15) * 128 + quad * 16) ^ xorv) >> 1);
    const int bbase = ((((wc * 64  + l15) * 128 + quad * 16) ^ xorv) >> 1);

    const int kStart = chunk * kLen;
    const int nt = kLen >> 6;

    f32x4 acc[8][4] = {};

#define STAGE(T, BUF)                                                          \
    {                                                                          \
        int kb_ = kStart + (T) * 64;                                           \
        const ushort* Ag_ = A + (long)m0 * aLd + kb_;                          \
        const ushort* Bg_ = Bb + segs.o[kb_ >> 10] + (long)inner * bZStride    \
                            + (long)n0 * 1024 + (kb_ & 1023);                  \
        ushort* lA_ = &lds[BUF][0];                                            \
        ushort* lB_ = &lds[BUF][16384];                                        \
        _Pragma("unroll")                                                      \
        for (int i_ = 0; i_ < 4; ++i_) {                                       \
            int br_ = (wave * 4 + i_) * 8 + srow;                              \
            gload16(Ag_ + (long)br_ * aLd + scolE, lA_ + (wave * 4 + i_) * 512); \
            gload16(Bg_ + (long)br_ * 1024 + scolE, lB_ + (wave * 4 + i_) * 512); \
        }                                                                      \
    }

#define PHASE(MQ, KQ, LOADB)                                                   \
    {                                                                          \
        if (LOADB) {                                                           \
            _Pragma("unroll")                                                  \
            for (int j_ = 0; j_ < 4; ++j_)                                     \
                bfr[j_] = *(const bf16x8*)&lB[bbase + j_ * 1024 + (KQ) * 32];  \
        }                                                                      \
        bf16x8 aa[4];                                                          \
        _Pragma("unroll")                                                      \
        for (int i_ = 0; i_ < 4; ++i_)                                         \
            aa[i_] = *(const bf16x8*)&lA[abase + ((MQ) * 4 + i_) * 1024 + (KQ) * 32]; \
        asm volatile("s_barrier" ::: "memory");                                \
        __builtin_amdgcn_s_setprio(1);                                         \
        _Pragma("unroll")                                                      \
        for (int i_ = 0; i_ < 4; ++i_) {                                       \
            _Pragma("unroll")                                                  \
            for (int j_ = 0; j_ < 4; ++j_)                                     \
                acc[(MQ) * 4 + i_][j_] = __builtin_amdgcn_mfma_f32_16x16x32_bf16( \
                    aa[i_], bfr[j_], acc[(MQ) * 4 + i_][j_], 0, 0, 0);         \
        }                                                                      \
        __builtin_amdgcn_s_setprio(0);                                         \
        asm volatile("s_barrier" ::: "memory");                                \
    }

    STAGE(0, 0);
    STAGE(1, 1);

    for (int t = 0; t < nt; ++t) {
        ushort* lA = &lds[t & 1][0];
        ushort* lB = &lds[t & 1][16384];
        if (t + 1 < nt) { asm volatile("s_waitcnt vmcnt(8)" ::: "memory"); }
        else            { asm volatile("s_waitcnt vmcnt(0)" ::: "memory"); }
        asm volatile("s_barrier" ::: "memory");
        bf16x8 bfr[4];
        PHASE(0, 0, 1);
        PHASE(1, 0, 0);
        PHASE(0, 1, 1);
        PHASE(1, 1, 0);
        if (t + 2 < nt) STAGE(t + 2, t & 1);
    }
#undef PHASE
#undef STAGE

    #pragma unroll
    for (int fm = 0; fm < 8; ++fm) {
        int row0 = m0 + wr * 128 + fm * 16 + quad * 4;
        #pragma unroll
        for (int fn = 0; fn < 4; ++fn) {
            int col = n0 + wc * 64 + fn * 16 + l15;
            #pragma unroll
            for (int r = 0; r < 4; ++r) {
                float v = acc[fm][fn][r] * scale;
                if (addI && chunk == 0 && pack == 0 && (row0 + r) == col) v += 1.0f;
                C[(long)(row0 + r) * cLd + col] = v;
            }
        }
    }
}

// ---------------------------------------------------------------------------
extern "C" void kernel_launch(void* const* d_in, const int* in_sizes, int n_in,
                              void* d_out, int out_size, void* d_ws, size_t ws_size,
                              hipStream_t stream)
{
    const float* x_re = (const float*)d_in[0];
    const float* x_im = (const float*)d_in[1];
    const float* U_re = (const float*)d_in[2];
    const float* U_im = (const float*)d_in[3];
    float* out = (float*)d_out;

    // ws layout (160 MiB):
    //   [0,48M):   6 fp32 planes [2][1024][1024]: Tre,Tim,Rre,Rim,BSre,BSim
    //   [48,96M):  Askew bf16 [4][1024][6144]  (later reused as A_apply [4][1024][4096])
    //              -> during SQUARINGS this region is dead: split-K partials live here
    //   [96,144M): At bf16 [4][1024][6144]   } reused as xT [2][4][4096][1024] (64 MiB)
    //              -> during HORNER this region is dead: split-K partials live here
    //   [144,160M): Tt bf16 [4][2][1024][1024]
    float* fp = (float*)d_ws;
    float* Tre = fp + 0L * 2 * PLANE;
    float* Tim = fp + 1L * 2 * PLANE;
    float* Rre = fp + 2L * 2 * PLANE;
    float* Rim = fp + 3L * 2 * PLANE;
    float* BSre = fp + 4L * 2 * PLANE;
    float* BSim = fp + 5L * 2 * PLANE;
    ushort* Askew = (ushort*)((char*)d_ws + (48L << 20));
    ushort* At    = (ushort*)((char*)d_ws + (96L << 20));
    ushort* Tt    = (ushort*)((char*)d_ws + (144L << 20));
    ushort* Aap   = Askew;
    ushort* xT    = At;
    float* Phorner = (float*)At;      // 48 MiB free during Horner
    float* Psquare = (float*)Askew;   // 48 MiB free during squarings

    dim3 blk(256);
    dim3 blk5(512);

    const float scaleB = 1.0f / 512.0f;   // ||skew|| ~128 -> ||B|| ~0.25, s=9
    build_skew_k<<<dim3(2 * PLANE / 256), blk, 0, stream>>>(U_re, U_im, BSre, BSim, scaleB);
    init_T_k<<<dim3(2 * PLANE / 256), blk, 0, stream>>>(BSre, BSim, Tre, Tim, 1.0f / 8.0f);
    pack_A6_k<<<dim3(2048), blk, 0, stream>>>(BSre, BSim, Askew);

    SegOff se;
    se.o[0] = 0L;           se.o[1] = 2L * PLANE;  se.o[2] = 0L;
    se.o[3] = 4L * PLANE;   se.o[4] = 6L * PLANE;  se.o[5] = 4L * PLANE;

    dim3 ge(4, 4, 16);                 // 4x4 xy tiles, 4 z * 4 K-chunks = 256 blocks (1/CU)
    dim3 gr(PLANE / 256);              // reduce: 4*PLANE floats / (256*4)
    // Horner: T <- I + (B @ T)/j
    for (int j = 7; j >= 1; --j) {
        pack_BT6_k<<<dim3(16, 16, 2), blk, 0, stream>>>(Tre, Tim, Tt);
        gemm256_k<<<ge, blk5, 0, stream>>>(Askew, 2L * 1024 * 6144, 1024L * 6144, 1, 6144,
                                           Tt, se, (long)PLANE,
                                           Rre, Rim, (long)PLANE, 1024,
                                           1536, 2, 1.0f, 0, Phorner);
        reduce_k<<<gr, blk, 0, stream>>>(Rre, Phorner, 1.0f / (float)j, 1);
        float* t;
        t = Tre; Tre = Rre; Rre = t;
        t = Tim; Tim = Rim; Rim = t;
    }
    // 9 squarings: T <- T @ T
    for (int s = 0; s < 9; ++s) {
        pack_A6_k<<<dim3(2048), blk, 0, stream>>>(Tre, Tim, At);
        pack_BT6_k<<<dim3(16, 16, 2), blk, 0, stream>>>(Tre, Tim, Tt);
        gemm256_k<<<ge, blk5, 0, stream>>>(At, 2L * 1024 * 6144, 1024L * 6144, 1, 6144,
                                           Tt, se, (long)PLANE,
                                           Rre, Rim, (long)PLANE, 1024,
                                           1536, 2, 1.0f, 0, Psquare);
        reduce_k<<<gr, blk, 0, stream>>>(Rre, Psquare, 1.0f, 0);
        float* t;
        t = Tre; Tre = Rre; Rre = t;
        t = Tim; Tim = Rim; Rim = t;
    }

    // Apply: out[k,b1] = U[k] @ X[k,b1]
    pack_A4_k<<<dim3(2048), blk, 0, stream>>>(Tre, Tim, Aap);
    pack_xT_k<<<dim3(64, 16, 4), blk, 0, stream>>>(x_re, x_im, xT);

    SegOff sa;
    sa.o[0] = 0L;        sa.o[1] = 0L;
    sa.o[2] = 4L << 22;  sa.o[3] = 4L << 22;
    sa.o[4] = 0L;        sa.o[5] = 0L;

    gemm256_k<<<dim3(16, 4, 8), blk5, 0, stream>>>(Aap, 2L * 1024 * 4096, 1024L * 4096, 2, 4096,
                                                   xT, sa, 1L << 22,
                                                   out, out + (1L << 24), 1L << 22, 4096,
                                                   4096, 4, 1.0f, 0, (float*)nullptr);
}

// Round 3
// 2134.073 us; speedup vs baseline: 1.3191x; 1.0524x over previous
//
#include <hip/hip_runtime.h>
#include <hip/hip_bf16.h>

#define PLANE (1 << 20)   // 1024*1024

typedef __attribute__((ext_vector_type(8))) short bf16x8;
typedef __attribute__((ext_vector_type(4))) float f32x4;

struct SegOff { long o[6]; };

union U4 { ushort u[4]; unsigned long long v; };

__device__ __forceinline__ ushort bf16bits(float v) {
    union { __hip_bfloat16 b; ushort u; } c;
    c.b = __float2bfloat16(v);
    return c.u;
}

__device__ __forceinline__ void split2(float v, ushort& hi, ushort& lo) {
    union { __hip_bfloat16 b; ushort u; } c;
    __hip_bfloat16 h = __float2bfloat16(v);
    c.b = h; hi = c.u;
    c.b = __float2bfloat16(v - __bfloat162float(h));
    lo = c.u;
}

__device__ __forceinline__ void gload16(const ushort* g, ushort* l) {
    __builtin_amdgcn_global_load_lds(
        (const __attribute__((address_space(1))) unsigned int*)g,
        (__attribute__((address_space(3))) unsigned int*)l, 16, 0, 0);
}

// ---------------------------------------------------------------------------
// B = (A - A^H) * scale
// ---------------------------------------------------------------------------
__global__ __launch_bounds__(256) void build_skew_k(
    const float* __restrict__ Ure, const float* __restrict__ Uim,
    float* __restrict__ Bre, float* __restrict__ Bim, float scale)
{
    int idx = blockIdx.x * 256 + threadIdx.x;
    int ij  = idx & (PLANE - 1);
    int i   = ij >> 10, j = ij & 1023;
    int t   = (idx & ~(PLANE - 1)) | (j << 10) | i;
    Bre[idx] = (Ure[idx] - Ure[t]) * scale;
    Bim[idx] = (Uim[idx] + Uim[t]) * scale;
}

// T = I + B * inv
__global__ __launch_bounds__(256) void init_T_k(
    const float* __restrict__ Bre, const float* __restrict__ Bim,
    float* __restrict__ Tre, float* __restrict__ Tim, float inv)
{
    int idx = blockIdx.x * 256 + threadIdx.x;
    int ij  = idx & (PLANE - 1);
    int i   = ij >> 10, j = ij & 1023;
    Tre[idx] = Bre[idx] * inv + ((i == j) ? 1.0f : 0.0f);
    Tim[idx] = Bim[idx] * inv;
}

// ---------------------------------------------------------------------------
// Split-K reduction: C = (C + P0 + P1 + P2) * scale  [+ I on real diagonal]
// ---------------------------------------------------------------------------
__global__ __launch_bounds__(256) void reduce_k(
    float* __restrict__ C, const float* __restrict__ PB, float scale, int addI)
{
    long e = ((long)blockIdx.x * 256 + threadIdx.x) * 4;   // 4*PLANE floats total
    float4 v = *(float4*)(C + e);
    const float4 a = *(const float4*)(PB + e);
    const float4 b = *(const float4*)(PB + 4L * PLANE + e);
    const float4 c = *(const float4*)(PB + 8L * PLANE + e);
    v.x = (v.x + a.x + b.x + c.x) * scale;
    v.y = (v.y + a.y + b.y + c.y) * scale;
    v.z = (v.z + a.z + b.z + c.z) * scale;
    v.w = (v.w + a.w + b.w + c.w) * scale;
    if (addI) {
        long p = e >> 20;                 // plane index 0..3 (0,1 = real part)
        if (p < 2) {
            int ij = (int)(e & (PLANE - 1));
            int i = ij >> 10, j = ij & 1023;
            if (i >= j && i < j + 4) ((float*)&v)[i - j] += 1.0f;
        }
    }
    *(float4*)(C + e) = v;
}

// ---------------------------------------------------------------------------
// Pack A (expm, 6 segments): Ab[4 z][1024][6144]
// ---------------------------------------------------------------------------
__global__ __launch_bounds__(256) void pack_A6_k(
    const float* __restrict__ Sre, const float* __restrict__ Sim,
    ushort* __restrict__ Ab)
{
    int idx = blockIdx.x * 256 + threadIdx.x;     // 524288 threads
    int k   = idx >> 18;
    int m   = (idx >> 8) & 1023;
    int c4  = (idx & 255) * 4;
    const float4 vr = *(const float4*)(Sre + (size_t)k * PLANE + (size_t)m * 1024 + c4);
    const float4 vi = *(const float4*)(Sim + (size_t)k * PLANE + (size_t)m * 1024 + c4);
    U4 rh, rl, ih, il, nih, nil;
    split2(vr.x, rh.u[0], rl.u[0]); split2(vr.y, rh.u[1], rl.u[1]);
    split2(vr.z, rh.u[2], rl.u[2]); split2(vr.w, rh.u[3], rl.u[3]);
    split2(vi.x, ih.u[0], il.u[0]); split2(vi.y, ih.u[1], il.u[1]);
    split2(vi.z, ih.u[2], il.u[2]); split2(vi.w, ih.u[3], il.u[3]);
    #pragma unroll
    for (int i = 0; i < 4; ++i) { nih.u[i] = ih.u[i] ^ 0x8000; nil.u[i] = il.u[i] ^ 0x8000; }

    long b0 = (long)k * 1024 * 6144 + (long)m * 6144;
    long b1 = (long)(2 + k) * 1024 * 6144 + (long)m * 6144;
    *(unsigned long long*)&Ab[b0 + 0*1024 + c4] = rh.v;
    *(unsigned long long*)&Ab[b0 + 1*1024 + c4] = rh.v;
    *(unsigned long long*)&Ab[b0 + 2*1024 + c4] = rl.v;
    *(unsigned long long*)&Ab[b0 + 3*1024 + c4] = nih.v;
    *(unsigned long long*)&Ab[b0 + 4*1024 + c4] = nih.v;
    *(unsigned long long*)&Ab[b0 + 5*1024 + c4] = nil.v;
    *(unsigned long long*)&Ab[b1 + 0*1024 + c4] = ih.v;
    *(unsigned long long*)&Ab[b1 + 1*1024 + c4] = ih.v;
    *(unsigned long long*)&Ab[b1 + 2*1024 + c4] = il.v;
    *(unsigned long long*)&Ab[b1 + 3*1024 + c4] = rh.v;
    *(unsigned long long*)&Ab[b1 + 4*1024 + c4] = rh.v;
    *(unsigned long long*)&Ab[b1 + 5*1024 + c4] = rl.v;
}

// ---------------------------------------------------------------------------
// Pack A (apply, 4 segments): Ab[4 z][1024][4096]
// ---------------------------------------------------------------------------
__global__ __launch_bounds__(256) void pack_A4_k(
    const float* __restrict__ Sre, const float* __restrict__ Sim,
    ushort* __restrict__ Ab)
{
    int idx = blockIdx.x * 256 + threadIdx.x;
    int k   = idx >> 18;
    int m   = (idx >> 8) & 1023;
    int c4  = (idx & 255) * 4;
    const float4 vr = *(const float4*)(Sre + (size_t)k * PLANE + (size_t)m * 1024 + c4);
    const float4 vi = *(const float4*)(Sim + (size_t)k * PLANE + (size_t)m * 1024 + c4);
    U4 rh, rl, ih, il, nih, nil;
    split2(vr.x, rh.u[0], rl.u[0]); split2(vr.y, rh.u[1], rl.u[1]);
    split2(vr.z, rh.u[2], rl.u[2]); split2(vr.w, rh.u[3], rl.u[3]);
    split2(vi.x, ih.u[0], il.u[0]); split2(vi.y, ih.u[1], il.u[1]);
    split2(vi.z, ih.u[2], il.u[2]); split2(vi.w, ih.u[3], il.u[3]);
    #pragma unroll
    for (int i = 0; i < 4; ++i) { nih.u[i] = ih.u[i] ^ 0x8000; nil.u[i] = il.u[i] ^ 0x8000; }

    long b0 = (long)k * 1024 * 4096 + (long)m * 4096;
    long b1 = (long)(2 + k) * 1024 * 4096 + (long)m * 4096;
    *(unsigned long long*)&Ab[b0 + 0*1024 + c4] = rh.v;
    *(unsigned long long*)&Ab[b0 + 1*1024 + c4] = rl.v;
    *(unsigned long long*)&Ab[b0 + 2*1024 + c4] = nih.v;
    *(unsigned long long*)&Ab[b0 + 3*1024 + c4] = nil.v;
    *(unsigned long long*)&Ab[b1 + 0*1024 + c4] = ih.v;
    *(unsigned long long*)&Ab[b1 + 1*1024 + c4] = il.v;
    *(unsigned long long*)&Ab[b1 + 2*1024 + c4] = rh.v;
    *(unsigned long long*)&Ab[b1 + 3*1024 + c4] = rl.v;
}

// ---------------------------------------------------------------------------
// Transpose + split T -> Tt[4 kind][2 k][1024][1024]  (kind: rh, rl, ih, il)
// ---------------------------------------------------------------------------
__global__ __launch_bounds__(256) void pack_BT6_k(
    const float* __restrict__ Sre, const float* __restrict__ Sim,
    ushort* __restrict__ Tt)
{
    __shared__ float Lre[64][65];
    __shared__ float Lim[64][65];
    int k = blockIdx.z, r0 = blockIdx.y * 64, c0 = blockIdx.x * 64;
    int tid = threadIdx.x;
    const float* br = Sre + (size_t)k * PLANE;
    const float* bi = Sim + (size_t)k * PLANE;
    #pragma unroll
    for (int p = 0; p < 16; ++p) {
        int idx = p * 256 + tid, r = idx >> 6, c = idx & 63;
        Lre[r][c] = br[(size_t)(r0 + r) * 1024 + c0 + c];
        Lim[r][c] = bi[(size_t)(r0 + r) * 1024 + c0 + c];
    }
    __syncthreads();
    #pragma unroll
    for (int p = 0; p < 4; ++p) {
        int s = p * 256 + tid, oc = s >> 4, r4 = (s & 15) * 4;
        U4 rh, rl, ih, il;
        #pragma unroll
        for (int i = 0; i < 4; ++i) {
            split2(Lre[r4 + i][oc], rh.u[i], rl.u[i]);
            split2(Lim[r4 + i][oc], ih.u[i], il.u[i]);
        }
        size_t dst = (size_t)k * PLANE + (size_t)(c0 + oc) * 1024 + r0 + r4;
        *(unsigned long long*)&Tt[0L * 2 * PLANE + dst] = rh.v;
        *(unsigned long long*)&Tt[1L * 2 * PLANE + dst] = rl.v;
        *(unsigned long long*)&Tt[2L * 2 * PLANE + dst] = ih.v;
        *(unsigned long long*)&Tt[3L * 2 * PLANE + dst] = il.v;
    }
}

// ---------------------------------------------------------------------------
// Transpose + convert x -> xT[2 kind][4 plane][4096][1024] (plain bf16)
// ---------------------------------------------------------------------------
__global__ __launch_bounds__(256) void pack_xT_k(
    const float* __restrict__ xre, const float* __restrict__ xim,
    ushort* __restrict__ xT)
{
    __shared__ float Lre[64][65];
    __shared__ float Lim[64][65];
    int pl = blockIdx.z, t0 = blockIdx.y * 64, c0 = blockIdx.x * 64;
    int tid = threadIdx.x;
    const float* br = xre + ((size_t)pl << 22);
    const float* bi = xim + ((size_t)pl << 22);
    #pragma unroll
    for (int p = 0; p < 16; ++p) {
        int idx = p * 256 + tid, r = idx >> 6, c = idx & 63;
        Lre[r][c] = br[(size_t)(t0 + r) * 4096 + c0 + c];
        Lim[r][c] = bi[(size_t)(t0 + r) * 4096 + c0 + c];
    }
    __syncthreads();
    #pragma unroll
    for (int p = 0; p < 4; ++p) {
        int s = p * 256 + tid, oc = s >> 4, r4 = (s & 15) * 4;
        U4 re4, im4;
        #pragma unroll
        for (int i = 0; i < 4; ++i) {
            re4.u[i] = bf16bits(Lre[r4 + i][oc]);
            im4.u[i] = bf16bits(Lim[r4 + i][oc]);
        }
        size_t dst = ((size_t)pl << 22) + (size_t)(c0 + oc) * 1024 + t0 + r4;
        *(unsigned long long*)&xT[dst] = re4.v;
        *(unsigned long long*)&xT[(4L << 22) + dst] = im4.v;
    }
}

// ---------------------------------------------------------------------------
// 256x256-tile 8-phase bf16 MFMA GEMM (T2 swizzle + T3/T4 counted vmcnt + T5).
// 512 threads = 8 waves (2M x 4N), per-wave output 128x64, BK=64.
// LDS 128 KiB: 2 buffers x (A 256x64 + B 256x64) bf16, 128-B rows.
// Swizzle (full 3-bit, Guideline-4 form): byte ^= ((row & 7) << 4).
//   - fragment ds_read_b128 (16 rows x quad*16B) spreads 8 lanes on each of
//     the 8 16-B slots per 128-B line -> conflict-free (wave64 b128 floor).
//   - global_load_lds dest stays LINEAR; inverse swizzle applied to the
//     per-lane GLOBAL source column: elemCol = ((lane&7) ^ (lane>>3)) * 8.
//   - read bases pre-XOR'd per thread; KQ*64B folded into two bases (XOR
//     touches byte-bit-6, so KQ can't be additive); 16-row phase offsets
//     (2048 B, bits >= 11) remain additive.
// Staging depth 2, vmcnt(8) at tile top (never drains to 0 mid-loop).
// ---------------------------------------------------------------------------
__global__ __launch_bounds__(512, 2) void gemm256_k(
    const ushort* __restrict__ Ab, long aPackStride, long aInnerStride, int aInnerDiv, int aLd,
    const ushort* __restrict__ Bb, SegOff segs, long bZStride,
    float* __restrict__ CreB, float* __restrict__ CimB, long cZStride, int cLd,
    int kLen, int zHalf, float scale, int addI,
    float* __restrict__ PB)
{
    __shared__ ushort lds[2][32768];   // per buf: A [0,16384), B [16384,32768) ushorts

    const int zTot  = 2 * zHalf;
    const int chunk = blockIdx.z / zTot;
    const int zb    = blockIdx.z % zTot;
    const int pack  = zb / zHalf, inner = zb % zHalf;
    const ushort* A = Ab + (long)pack * aPackStride + (long)(inner / aInnerDiv) * aInnerStride;
    float* C = (chunk == 0)
        ? ((pack ? CimB : CreB) + (long)inner * cZStride)
        : (PB + (long)(chunk - 1) * 4 * PLANE + (long)pack * 2 * PLANE + (long)inner * PLANE);

    const int tid  = threadIdx.x;
    const int lane = tid & 63, wave = tid >> 6;
    const int wr = wave >> 2, wc = wave & 3;       // 2M x 4N wave grid
    const int l15 = lane & 15, quad = lane >> 4;
    const int m0 = blockIdx.y * 256, n0 = blockIdx.x * 256;

    // staging thread-constants: linear LDS dest, inverse-swizzled global col
    const int srow  = lane >> 3;                         // row within 8-row group
    const int scolE = ((lane & 7) ^ srow) * 8;           // element col 0..56
    // fragment-read bases (ushort units), fully pre-swizzled
    const int swz  = (l15 & 7) << 4;                     // byte XOR, bits 4-6
    const int rA   = (wr * 128 + l15) * 128;             // row byte base (A)
    const int rB   = (wc * 64  + l15) * 128;             // row byte base (B)
    const int ab0  = ((rA + quad * 16)      ^ swz) >> 1;
    const int ab1  = ((rA + quad * 16 + 64) ^ swz) >> 1;
    const int bb0  = ((rB + quad * 16)      ^ swz) >> 1;
    const int bb1  = ((rB + quad * 16 + 64) ^ swz) >> 1;

    const int kStart = chunk * kLen;
    const int nt = kLen >> 6;

    f32x4 acc[8][4] = {};

#define STAGE(T, BUF)                                                          \
    {                                                                          \
        int kb_ = kStart + (T) * 64;                                           \
        const ushort* Ag_ = A + (long)m0 * aLd + kb_;                          \
        const ushort* Bg_ = Bb + segs.o[kb_ >> 10] + (long)inner * bZStride    \
                            + (long)n0 * 1024 + (kb_ & 1023);                  \
        ushort* lA_ = &lds[BUF][0];                                            \
        ushort* lB_ = &lds[BUF][16384];                                        \
        _Pragma("unroll")                                                      \
        for (int i_ = 0; i_ < 4; ++i_) {                                       \
            int br_ = (wave * 4 + i_) * 8 + srow;                              \
            gload16(Ag_ + (long)br_ * aLd + scolE, lA_ + (wave * 4 + i_) * 512); \
            gload16(Bg_ + (long)br_ * 1024 + scolE, lB_ + (wave * 4 + i_) * 512); \
        }                                                                      \
    }

#define PHASE(MQ, KQ, LOADB)                                                   \
    {                                                                          \
        const int ab_ = (KQ) ? ab1 : ab0;                                      \
        const int bb_ = (KQ) ? bb1 : bb0;                                      \
        if (LOADB) {                                                           \
            _Pragma("unroll")                                                  \
            for (int j_ = 0; j_ < 4; ++j_)                                     \
                bfr[j_] = *(const bf16x8*)&lB[bb_ + j_ * 1024];                \
        }                                                                      \
        bf16x8 aa[4];                                                          \
        _Pragma("unroll")                                                      \
        for (int i_ = 0; i_ < 4; ++i_)                                         \
            aa[i_] = *(const bf16x8*)&lA[ab_ + ((MQ) * 4 + i_) * 1024];        \
        asm volatile("s_barrier" ::: "memory");                                \
        __builtin_amdgcn_s_setprio(1);                                         \
        _Pragma("unroll")                                                      \
        for (int i_ = 0; i_ < 4; ++i_) {                                       \
            _Pragma("unroll")                                                  \
            for (int j_ = 0; j_ < 4; ++j_)                                     \
                acc[(MQ) * 4 + i_][j_] = __builtin_amdgcn_mfma_f32_16x16x32_bf16( \
                    aa[i_], bfr[j_], acc[(MQ) * 4 + i_][j_], 0, 0, 0);         \
        }                                                                      \
        __builtin_amdgcn_s_setprio(0);                                         \
        asm volatile("s_barrier" ::: "memory");                                \
    }

    STAGE(0, 0);
    STAGE(1, 1);

    for (int t = 0; t < nt; ++t) {
        ushort* lA = &lds[t & 1][0];
        ushort* lB = &lds[t & 1][16384];
        if (t + 1 < nt) { asm volatile("s_waitcnt vmcnt(8)" ::: "memory"); }
        else            { asm volatile("s_waitcnt vmcnt(0)" ::: "memory"); }
        asm volatile("s_barrier" ::: "memory");
        bf16x8 bfr[4];
        PHASE(0, 0, 1);
        PHASE(1, 0, 0);
        PHASE(0, 1, 1);
        PHASE(1, 1, 0);
        if (t + 2 < nt) STAGE(t + 2, t & 1);
    }
#undef PHASE
#undef STAGE

    #pragma unroll
    for (int fm = 0; fm < 8; ++fm) {
        int row0 = m0 + wr * 128 + fm * 16 + quad * 4;
        #pragma unroll
        for (int fn = 0; fn < 4; ++fn) {
            int col = n0 + wc * 64 + fn * 16 + l15;
            #pragma unroll
            for (int r = 0; r < 4; ++r) {
                float v = acc[fm][fn][r] * scale;
                if (addI && chunk == 0 && pack == 0 && (row0 + r) == col) v += 1.0f;
                C[(long)(row0 + r) * cLd + col] = v;
            }
        }
    }
}

// ---------------------------------------------------------------------------
extern "C" void kernel_launch(void* const* d_in, const int* in_sizes, int n_in,
                              void* d_out, int out_size, void* d_ws, size_t ws_size,
                              hipStream_t stream)
{
    const float* x_re = (const float*)d_in[0];
    const float* x_im = (const float*)d_in[1];
    const float* U_re = (const float*)d_in[2];
    const float* U_im = (const float*)d_in[3];
    float* out = (float*)d_out;

    // ws layout (160 MiB):
    //   [0,48M):   6 fp32 planes [2][1024][1024]: Tre,Tim,Rre,Rim,BSre,BSim
    //   [48,96M):  Askew bf16 [4][1024][6144]  (later reused as A_apply [4][1024][4096])
    //              -> during SQUARINGS this region is dead: split-K partials live here
    //   [96,144M): At bf16 [4][1024][6144]   } reused as xT [2][4][4096][1024] (64 MiB)
    //              -> during HORNER this region is dead: split-K partials live here
    //   [144,160M): Tt bf16 [4][2][1024][1024]
    float* fp = (float*)d_ws;
    float* Tre = fp + 0L * 2 * PLANE;
    float* Tim = fp + 1L * 2 * PLANE;
    float* Rre = fp + 2L * 2 * PLANE;
    float* Rim = fp + 3L * 2 * PLANE;
    float* BSre = fp + 4L * 2 * PLANE;
    float* BSim = fp + 5L * 2 * PLANE;
    ushort* Askew = (ushort*)((char*)d_ws + (48L << 20));
    ushort* At    = (ushort*)((char*)d_ws + (96L << 20));
    ushort* Tt    = (ushort*)((char*)d_ws + (144L << 20));
    ushort* Aap   = Askew;
    ushort* xT    = At;
    float* Phorner = (float*)At;      // 48 MiB free during Horner
    float* Psquare = (float*)Askew;   // 48 MiB free during squarings

    dim3 blk(256);
    dim3 blk5(512);

    const float scaleB = 1.0f / 512.0f;   // ||skew|| ~128 -> ||B|| ~0.25, s=9
    build_skew_k<<<dim3(2 * PLANE / 256), blk, 0, stream>>>(U_re, U_im, BSre, BSim, scaleB);
    init_T_k<<<dim3(2 * PLANE / 256), blk, 0, stream>>>(BSre, BSim, Tre, Tim, 1.0f / 8.0f);
    pack_A6_k<<<dim3(2048), blk, 0, stream>>>(BSre, BSim, Askew);

    SegOff se;
    se.o[0] = 0L;           se.o[1] = 2L * PLANE;  se.o[2] = 0L;
    se.o[3] = 4L * PLANE;   se.o[4] = 6L * PLANE;  se.o[5] = 4L * PLANE;

    dim3 ge(4, 4, 16);                 // 4x4 xy tiles, 4 z * 4 K-chunks = 256 blocks (1/CU)
    dim3 gr(PLANE / 256);              // reduce: 4*PLANE floats / (256*4)
    // Horner: T <- I + (B @ T)/j
    for (int j = 7; j >= 1; --j) {
        pack_BT6_k<<<dim3(16, 16, 2), blk, 0, stream>>>(Tre, Tim, Tt);
        gemm256_k<<<ge, blk5, 0, stream>>>(Askew, 2L * 1024 * 6144, 1024L * 6144, 1, 6144,
                                           Tt, se, (long)PLANE,
                                           Rre, Rim, (long)PLANE, 1024,
                                           1536, 2, 1.0f, 0, Phorner);
        reduce_k<<<gr, blk, 0, stream>>>(Rre, Phorner, 1.0f / (float)j, 1);
        float* t;
        t = Tre; Tre = Rre; Rre = t;
        t = Tim; Tim = Rim; Rim = t;
    }
    // 9 squarings: T <- T @ T
    for (int s = 0; s < 9; ++s) {
        pack_A6_k<<<dim3(2048), blk, 0, stream>>>(Tre, Tim, At);
        pack_BT6_k<<<dim3(16, 16, 2), blk, 0, stream>>>(Tre, Tim, Tt);
        gemm256_k<<<ge, blk5, 0, stream>>>(At, 2L * 1024 * 6144, 1024L * 6144, 1, 6144,
                                           Tt, se, (long)PLANE,
                                           Rre, Rim, (long)PLANE, 1024,
                                           1536, 2, 1.0f, 0, Psquare);
        reduce_k<<<gr, blk, 0, stream>>>(Rre, Psquare, 1.0f, 0);
        float* t;
        t = Tre; Tre = Rre; Rre = t;
        t = Tim; Tim = Rim; Rim = t;
    }

    // Apply: out[k,b1] = U[k] @ X[k,b1]
    pack_A4_k<<<dim3(2048), blk, 0, stream>>>(Tre, Tim, Aap);
    pack_xT_k<<<dim3(64, 16, 4), blk, 0, stream>>>(x_re, x_im, xT);

    SegOff sa;
    sa.o[0] = 0L;        sa.o[1] = 0L;
    sa.o[2] = 4L << 22;  sa.o[3] = 4L << 22;
    sa.o[4] = 0L;        sa.o[5] = 0L;

    gemm256_k<<<dim3(16, 4, 8), blk5, 0, stream>>>(Aap, 2L * 1024 * 4096, 1024L * 4096, 2, 4096,
                                                   xT, sa, 1L << 22,
                                                   out, out + (1L << 24), 1L << 22, 4096,
                                                   4096, 4, 1.0f, 0, (float*)nullptr);
}

// Round 4
// 2086.676 us; speedup vs baseline: 1.3490x; 1.0227x over previous
//
#include <hip/hip_runtime.h>
#include <hip/hip_bf16.h>

#define PLANE (1 << 20)   // 1024*1024

typedef __attribute__((ext_vector_type(8))) short bf16x8;
typedef __attribute__((ext_vector_type(4))) float f32x4;

struct SegOff { long o[6]; };

union U4 { ushort u[4]; unsigned long long v; };

__device__ __forceinline__ ushort bf16bits(float v) {
    union { __hip_bfloat16 b; ushort u; } c;
    c.b = __float2bfloat16(v);
    return c.u;
}

__device__ __forceinline__ void split2(float v, ushort& hi, ushort& lo) {
    union { __hip_bfloat16 b; ushort u; } c;
    __hip_bfloat16 h = __float2bfloat16(v);
    c.b = h; hi = c.u;
    c.b = __float2bfloat16(v - __bfloat162float(h));
    lo = c.u;
}

__device__ __forceinline__ void gload16(const ushort* g, ushort* l) {
    __builtin_amdgcn_global_load_lds(
        (const __attribute__((address_space(1))) unsigned int*)g,
        (__attribute__((address_space(3))) unsigned int*)l, 16, 0, 0);
}

// ---------------------------------------------------------------------------
// B = (A - A^H) * scale
// ---------------------------------------------------------------------------
__global__ __launch_bounds__(256) void build_skew_k(
    const float* __restrict__ Ure, const float* __restrict__ Uim,
    float* __restrict__ Bre, float* __restrict__ Bim, float scale)
{
    int idx = blockIdx.x * 256 + threadIdx.x;
    int ij  = idx & (PLANE - 1);
    int i   = ij >> 10, j = ij & 1023;
    int t   = (idx & ~(PLANE - 1)) | (j << 10) | i;
    Bre[idx] = (Ure[idx] - Ure[t]) * scale;
    Bim[idx] = (Uim[idx] + Uim[t]) * scale;
}

// T = I + B * inv
__global__ __launch_bounds__(256) void init_T_k(
    const float* __restrict__ Bre, const float* __restrict__ Bim,
    float* __restrict__ Tre, float* __restrict__ Tim, float inv)
{
    int idx = blockIdx.x * 256 + threadIdx.x;
    int ij  = idx & (PLANE - 1);
    int i   = ij >> 10, j = ij & 1023;
    Tre[idx] = Bre[idx] * inv + ((i == j) ? 1.0f : 0.0f);
    Tim[idx] = Bim[idx] * inv;
}

// ---------------------------------------------------------------------------
// Split-K reduction: C = (C + P0 + P1 + P2) * scale  [+ I on real diagonal]
// ---------------------------------------------------------------------------
__global__ __launch_bounds__(256) void reduce_k(
    float* __restrict__ C, const float* __restrict__ PB, float scale, int addI)
{
    long e = ((long)blockIdx.x * 256 + threadIdx.x) * 4;   // 4*PLANE floats total
    float4 v = *(float4*)(C + e);
    const float4 a = *(const float4*)(PB + e);
    const float4 b = *(const float4*)(PB + 4L * PLANE + e);
    const float4 c = *(const float4*)(PB + 8L * PLANE + e);
    v.x = (v.x + a.x + b.x + c.x) * scale;
    v.y = (v.y + a.y + b.y + c.y) * scale;
    v.z = (v.z + a.z + b.z + c.z) * scale;
    v.w = (v.w + a.w + b.w + c.w) * scale;
    if (addI) {
        long p = e >> 20;                 // plane index 0..3 (0,1 = real part)
        if (p < 2) {
            int ij = (int)(e & (PLANE - 1));
            int i = ij >> 10, j = ij & 1023;
            if (i >= j && i < j + 4) ((float*)&v)[i - j] += 1.0f;
        }
    }
    *(float4*)(C + e) = v;
}

// ---------------------------------------------------------------------------
// Pack A (expm, 6 segments): Ab[4 z][1024][6144]
// ---------------------------------------------------------------------------
__global__ __launch_bounds__(256) void pack_A6_k(
    const float* __restrict__ Sre, const float* __restrict__ Sim,
    ushort* __restrict__ Ab)
{
    int idx = blockIdx.x * 256 + threadIdx.x;     // 524288 threads
    int k   = idx >> 18;
    int m   = (idx >> 8) & 1023;
    int c4  = (idx & 255) * 4;
    const float4 vr = *(const float4*)(Sre + (size_t)k * PLANE + (size_t)m * 1024 + c4);
    const float4 vi = *(const float4*)(Sim + (size_t)k * PLANE + (size_t)m * 1024 + c4);
    U4 rh, rl, ih, il, nih, nil;
    split2(vr.x, rh.u[0], rl.u[0]); split2(vr.y, rh.u[1], rl.u[1]);
    split2(vr.z, rh.u[2], rl.u[2]); split2(vr.w, rh.u[3], rl.u[3]);
    split2(vi.x, ih.u[0], il.u[0]); split2(vi.y, ih.u[1], il.u[1]);
    split2(vi.z, ih.u[2], il.u[2]); split2(vi.w, ih.u[3], il.u[3]);
    #pragma unroll
    for (int i = 0; i < 4; ++i) { nih.u[i] = ih.u[i] ^ 0x8000; nil.u[i] = il.u[i] ^ 0x8000; }

    long b0 = (long)k * 1024 * 6144 + (long)m * 6144;
    long b1 = (long)(2 + k) * 1024 * 6144 + (long)m * 6144;
    *(unsigned long long*)&Ab[b0 + 0*1024 + c4] = rh.v;
    *(unsigned long long*)&Ab[b0 + 1*1024 + c4] = rh.v;
    *(unsigned long long*)&Ab[b0 + 2*1024 + c4] = rl.v;
    *(unsigned long long*)&Ab[b0 + 3*1024 + c4] = nih.v;
    *(unsigned long long*)&Ab[b0 + 4*1024 + c4] = nih.v;
    *(unsigned long long*)&Ab[b0 + 5*1024 + c4] = nil.v;
    *(unsigned long long*)&Ab[b1 + 0*1024 + c4] = ih.v;
    *(unsigned long long*)&Ab[b1 + 1*1024 + c4] = ih.v;
    *(unsigned long long*)&Ab[b1 + 2*1024 + c4] = il.v;
    *(unsigned long long*)&Ab[b1 + 3*1024 + c4] = rh.v;
    *(unsigned long long*)&Ab[b1 + 4*1024 + c4] = rh.v;
    *(unsigned long long*)&Ab[b1 + 5*1024 + c4] = rl.v;
}

// ---------------------------------------------------------------------------
// Pack A (apply, 4 segments): Ab[4 z][1024][4096]
// ---------------------------------------------------------------------------
__global__ __launch_bounds__(256) void pack_A4_k(
    const float* __restrict__ Sre, const float* __restrict__ Sim,
    ushort* __restrict__ Ab)
{
    int idx = blockIdx.x * 256 + threadIdx.x;
    int k   = idx >> 18;
    int m   = (idx >> 8) & 1023;
    int c4  = (idx & 255) * 4;
    const float4 vr = *(const float4*)(Sre + (size_t)k * PLANE + (size_t)m * 1024 + c4);
    const float4 vi = *(const float4*)(Sim + (size_t)k * PLANE + (size_t)m * 1024 + c4);
    U4 rh, rl, ih, il, nih, nil;
    split2(vr.x, rh.u[0], rl.u[0]); split2(vr.y, rh.u[1], rl.u[1]);
    split2(vr.z, rh.u[2], rl.u[2]); split2(vr.w, rh.u[3], rl.u[3]);
    split2(vi.x, ih.u[0], il.u[0]); split2(vi.y, ih.u[1], il.u[1]);
    split2(vi.z, ih.u[2], il.u[2]); split2(vi.w, ih.u[3], il.u[3]);
    #pragma unroll
    for (int i = 0; i < 4; ++i) { nih.u[i] = ih.u[i] ^ 0x8000; nil.u[i] = il.u[i] ^ 0x8000; }

    long b0 = (long)k * 1024 * 4096 + (long)m * 4096;
    long b1 = (long)(2 + k) * 1024 * 4096 + (long)m * 4096;
    *(unsigned long long*)&Ab[b0 + 0*1024 + c4] = rh.v;
    *(unsigned long long*)&Ab[b0 + 1*1024 + c4] = rl.v;
    *(unsigned long long*)&Ab[b0 + 2*1024 + c4] = nih.v;
    *(unsigned long long*)&Ab[b0 + 3*1024 + c4] = nil.v;
    *(unsigned long long*)&Ab[b1 + 0*1024 + c4] = ih.v;
    *(unsigned long long*)&Ab[b1 + 1*1024 + c4] = il.v;
    *(unsigned long long*)&Ab[b1 + 2*1024 + c4] = rh.v;
    *(unsigned long long*)&Ab[b1 + 3*1024 + c4] = rl.v;
}

// ---------------------------------------------------------------------------
// Transpose + split T -> Tt[4 kind][2 k][1024][1024]  (kind: rh, rl, ih, il)
// ---------------------------------------------------------------------------
__global__ __launch_bounds__(256) void pack_BT6_k(
    const float* __restrict__ Sre, const float* __restrict__ Sim,
    ushort* __restrict__ Tt)
{
    __shared__ float Lre[64][65];
    __shared__ float Lim[64][65];
    int k = blockIdx.z, r0 = blockIdx.y * 64, c0 = blockIdx.x * 64;
    int tid = threadIdx.x;
    const float* br = Sre + (size_t)k * PLANE;
    const float* bi = Sim + (size_t)k * PLANE;
    #pragma unroll
    for (int p = 0; p < 16; ++p) {
        int idx = p * 256 + tid, r = idx >> 6, c = idx & 63;
        Lre[r][c] = br[(size_t)(r0 + r) * 1024 + c0 + c];
        Lim[r][c] = bi[(size_t)(r0 + r) * 1024 + c0 + c];
    }
    __syncthreads();
    #pragma unroll
    for (int p = 0; p < 4; ++p) {
        int s = p * 256 + tid, oc = s >> 4, r4 = (s & 15) * 4;
        U4 rh, rl, ih, il;
        #pragma unroll
        for (int i = 0; i < 4; ++i) {
            split2(Lre[r4 + i][oc], rh.u[i], rl.u[i]);
            split2(Lim[r4 + i][oc], ih.u[i], il.u[i]);
        }
        size_t dst = (size_t)k * PLANE + (size_t)(c0 + oc) * 1024 + r0 + r4;
        *(unsigned long long*)&Tt[0L * 2 * PLANE + dst] = rh.v;
        *(unsigned long long*)&Tt[1L * 2 * PLANE + dst] = rl.v;
        *(unsigned long long*)&Tt[2L * 2 * PLANE + dst] = ih.v;
        *(unsigned long long*)&Tt[3L * 2 * PLANE + dst] = il.v;
    }
}

// ---------------------------------------------------------------------------
// Transpose + convert x -> xT[2 kind][4 plane][4096][1024] (plain bf16)
// ---------------------------------------------------------------------------
__global__ __launch_bounds__(256) void pack_xT_k(
    const float* __restrict__ xre, const float* __restrict__ xim,
    ushort* __restrict__ xT)
{
    __shared__ float Lre[64][65];
    __shared__ float Lim[64][65];
    int pl = blockIdx.z, t0 = blockIdx.y * 64, c0 = blockIdx.x * 64;
    int tid = threadIdx.x;
    const float* br = xre + ((size_t)pl << 22);
    const float* bi = xim + ((size_t)pl << 22);
    #pragma unroll
    for (int p = 0; p < 16; ++p) {
        int idx = p * 256 + tid, r = idx >> 6, c = idx & 63;
        Lre[r][c] = br[(size_t)(t0 + r) * 4096 + c0 + c];
        Lim[r][c] = bi[(size_t)(t0 + r) * 4096 + c0 + c];
    }
    __syncthreads();
    #pragma unroll
    for (int p = 0; p < 4; ++p) {
        int s = p * 256 + tid, oc = s >> 4, r4 = (s & 15) * 4;
        U4 re4, im4;
        #pragma unroll
        for (int i = 0; i < 4; ++i) {
            re4.u[i] = bf16bits(Lre[r4 + i][oc]);
            im4.u[i] = bf16bits(Lim[r4 + i][oc]);
        }
        size_t dst = ((size_t)pl << 22) + (size_t)(c0 + oc) * 1024 + t0 + r4;
        *(unsigned long long*)&xT[dst] = re4.v;
        *(unsigned long long*)&xT[(4L << 22) + dst] = im4.v;
    }
}

// ---------------------------------------------------------------------------
// 256x256-tile bf16 MFMA GEMM, minimal-barrier schedule.
// 512 threads = 8 waves (2M x 4N), per-wave output 128x64, BK=64.
// LDS 128 KiB: 2 buffers x (A 256x64 + B 256x64) bf16, 128-B rows.
// Swizzle (full 3-bit, conflict-free, verified R3): byte ^= ((row&7)<<4);
//   linear global_load_lds dest + inverse-swizzled global source column.
// Schedule: 2 barriers per tile ONLY.
//   - tile top: vmcnt(8) (tile t's loads done; t+1's 8 stay in flight) + barrier
//   - after tile body: barrier (all waves consumed buf[t&1]) then STAGE(t+2).
// Intra-tile: straight-line 24 ds_read_b128 + 64 MFMA; compiler interleaves
// (fine lgkmcnt), so LDS transfer overlaps the matrix pipe instead of
// serializing in barrier-lockstep windows (R3's residual bottleneck).
// ---------------------------------------------------------------------------
__global__ __launch_bounds__(512, 2) void gemm256_k(
    const ushort* __restrict__ Ab, long aPackStride, long aInnerStride, int aInnerDiv, int aLd,
    const ushort* __restrict__ Bb, SegOff segs, long bZStride,
    float* __restrict__ CreB, float* __restrict__ CimB, long cZStride, int cLd,
    int kLen, int zHalf, float scale, int addI,
    float* __restrict__ PB)
{
    __shared__ ushort lds[2][32768];   // per buf: A [0,16384), B [16384,32768) ushorts

    const int zTot  = 2 * zHalf;
    const int chunk = blockIdx.z / zTot;
    const int zb    = blockIdx.z % zTot;
    const int pack  = zb / zHalf, inner = zb % zHalf;
    const ushort* A = Ab + (long)pack * aPackStride + (long)(inner / aInnerDiv) * aInnerStride;
    float* C = (chunk == 0)
        ? ((pack ? CimB : CreB) + (long)inner * cZStride)
        : (PB + (long)(chunk - 1) * 4 * PLANE + (long)pack * 2 * PLANE + (long)inner * PLANE);

    const int tid  = threadIdx.x;
    const int lane = tid & 63, wave = tid >> 6;
    const int wr = wave >> 2, wc = wave & 3;       // 2M x 4N wave grid
    const int l15 = lane & 15, quad = lane >> 4;
    const int m0 = blockIdx.y * 256, n0 = blockIdx.x * 256;

    // staging thread-constants: linear LDS dest, inverse-swizzled global col
    const int srow  = lane >> 3;                         // row within 8-row group
    const int scolE = ((lane & 7) ^ srow) * 8;           // element col 0..56
    // fragment-read bases (ushort units), fully pre-swizzled
    const int swz  = (l15 & 7) << 4;                     // byte XOR, bits 4-6
    const int rA   = (wr * 128 + l15) * 128;             // row byte base (A)
    const int rB   = (wc * 64  + l15) * 128;             // row byte base (B)
    const int ab0  = ((rA + quad * 16)      ^ swz) >> 1;
    const int ab1  = ((rA + quad * 16 + 64) ^ swz) >> 1;
    const int bb0  = ((rB + quad * 16)      ^ swz) >> 1;
    const int bb1  = ((rB + quad * 16 + 64) ^ swz) >> 1;

    const int kStart = chunk * kLen;
    const int nt = kLen >> 6;

    f32x4 acc[8][4] = {};

#define STAGE(T, BUF)                                                          \
    {                                                                          \
        int kb_ = kStart + (T) * 64;                                           \
        const ushort* Ag_ = A + (long)m0 * aLd + kb_;                          \
        const ushort* Bg_ = Bb + segs.o[kb_ >> 10] + (long)inner * bZStride    \
                            + (long)n0 * 1024 + (kb_ & 1023);                  \
        ushort* lA_ = &lds[BUF][0];                                            \
        ushort* lB_ = &lds[BUF][16384];                                        \
        _Pragma("unroll")                                                      \
        for (int i_ = 0; i_ < 4; ++i_) {                                       \
            int br_ = (wave * 4 + i_) * 8 + srow;                              \
            gload16(Ag_ + (long)br_ * aLd + scolE, lA_ + (wave * 4 + i_) * 512); \
            gload16(Bg_ + (long)br_ * 1024 + scolE, lB_ + (wave * 4 + i_) * 512); \
        }                                                                      \
    }

// One quadrant-group: 4 A-frags x 4 B-frags over one K-quadrant (16 MFMA).
// No barriers: compiler schedules ds_reads against MFMAs freely.
#define PHASE(MQ, KQ, LOADB)                                                   \
    {                                                                          \
        const int ab_ = (KQ) ? ab1 : ab0;                                      \
        const int bb_ = (KQ) ? bb1 : bb0;                                      \
        if (LOADB) {                                                           \
            _Pragma("unroll")                                                  \
            for (int j_ = 0; j_ < 4; ++j_)                                     \
                bfr[j_] = *(const bf16x8*)&lB[bb_ + j_ * 1024];                \
        }                                                                      \
        bf16x8 aa[4];                                                          \
        _Pragma("unroll")                                                      \
        for (int i_ = 0; i_ < 4; ++i_)                                         \
            aa[i_] = *(const bf16x8*)&lA[ab_ + ((MQ) * 4 + i_) * 1024];        \
        __builtin_amdgcn_s_setprio(1);                                         \
        _Pragma("unroll")                                                      \
        for (int i_ = 0; i_ < 4; ++i_) {                                       \
            _Pragma("unroll")                                                  \
            for (int j_ = 0; j_ < 4; ++j_)                                     \
                acc[(MQ) * 4 + i_][j_] = __builtin_amdgcn_mfma_f32_16x16x32_bf16( \
                    aa[i_], bfr[j_], acc[(MQ) * 4 + i_][j_], 0, 0, 0);         \
        }                                                                      \
        __builtin_amdgcn_s_setprio(0);                                         \
    }

    STAGE(0, 0);
    STAGE(1, 1);

    for (int t = 0; t < nt; ++t) {
        ushort* lA = &lds[t & 1][0];
        ushort* lB = &lds[t & 1][16384];
        if (t + 1 < nt) { asm volatile("s_waitcnt vmcnt(8)" ::: "memory"); }
        else            { asm volatile("s_waitcnt vmcnt(0)" ::: "memory"); }
        asm volatile("s_barrier" ::: "memory");   // buf[t&1] visible to all
        bf16x8 bfr[4];
        PHASE(0, 0, 1);
        PHASE(1, 0, 0);
        PHASE(0, 1, 1);
        PHASE(1, 1, 0);
        asm volatile("s_barrier" ::: "memory");   // all waves done reading buf[t&1]
        if (t + 2 < nt) STAGE(t + 2, t & 1);
    }
#undef PHASE
#undef STAGE

    #pragma unroll
    for (int fm = 0; fm < 8; ++fm) {
        int row0 = m0 + wr * 128 + fm * 16 + quad * 4;
        #pragma unroll
        for (int fn = 0; fn < 4; ++fn) {
            int col = n0 + wc * 64 + fn * 16 + l15;
            #pragma unroll
            for (int r = 0; r < 4; ++r) {
                float v = acc[fm][fn][r] * scale;
                if (addI && chunk == 0 && pack == 0 && (row0 + r) == col) v += 1.0f;
                C[(long)(row0 + r) * cLd + col] = v;
            }
        }
    }
}

// ---------------------------------------------------------------------------
extern "C" void kernel_launch(void* const* d_in, const int* in_sizes, int n_in,
                              void* d_out, int out_size, void* d_ws, size_t ws_size,
                              hipStream_t stream)
{
    const float* x_re = (const float*)d_in[0];
    const float* x_im = (const float*)d_in[1];
    const float* U_re = (const float*)d_in[2];
    const float* U_im = (const float*)d_in[3];
    float* out = (float*)d_out;

    // ws layout (160 MiB):
    //   [0,48M):   6 fp32 planes [2][1024][1024]: Tre,Tim,Rre,Rim,BSre,BSim
    //   [48,96M):  Askew bf16 [4][1024][6144]  (later reused as A_apply [4][1024][4096])
    //              -> during SQUARINGS this region is dead: split-K partials live here
    //   [96,144M): At bf16 [4][1024][6144]   } reused as xT [2][4][4096][1024] (64 MiB)
    //              -> during HORNER this region is dead: split-K partials live here
    //   [144,160M): Tt bf16 [4][2][1024][1024]
    float* fp = (float*)d_ws;
    float* Tre = fp + 0L * 2 * PLANE;
    float* Tim = fp + 1L * 2 * PLANE;
    float* Rre = fp + 2L * 2 * PLANE;
    float* Rim = fp + 3L * 2 * PLANE;
    float* BSre = fp + 4L * 2 * PLANE;
    float* BSim = fp + 5L * 2 * PLANE;
    ushort* Askew = (ushort*)((char*)d_ws + (48L << 20));
    ushort* At    = (ushort*)((char*)d_ws + (96L << 20));
    ushort* Tt    = (ushort*)((char*)d_ws + (144L << 20));
    ushort* Aap   = Askew;
    ushort* xT    = At;
    float* Phorner = (float*)At;      // 48 MiB free during Horner
    float* Psquare = (float*)Askew;   // 48 MiB free during squarings

    dim3 blk(256);
    dim3 blk5(512);

    const float scaleB = 1.0f / 512.0f;   // ||skew|| ~128 -> ||B|| ~0.25, s=9
    build_skew_k<<<dim3(2 * PLANE / 256), blk, 0, stream>>>(U_re, U_im, BSre, BSim, scaleB);
    init_T_k<<<dim3(2 * PLANE / 256), blk, 0, stream>>>(BSre, BSim, Tre, Tim, 1.0f / 8.0f);
    pack_A6_k<<<dim3(2048), blk, 0, stream>>>(BSre, BSim, Askew);

    SegOff se;
    se.o[0] = 0L;           se.o[1] = 2L * PLANE;  se.o[2] = 0L;
    se.o[3] = 4L * PLANE;   se.o[4] = 6L * PLANE;  se.o[5] = 4L * PLANE;

    dim3 ge(4, 4, 16);                 // 4x4 xy tiles, 4 z * 4 K-chunks = 256 blocks (1/CU)
    dim3 gr(PLANE / 256);              // reduce: 4*PLANE floats / (256*4)
    // Horner: T <- I + (B @ T)/j
    for (int j = 7; j >= 1; --j) {
        pack_BT6_k<<<dim3(16, 16, 2), blk, 0, stream>>>(Tre, Tim, Tt);
        gemm256_k<<<ge, blk5, 0, stream>>>(Askew, 2L * 1024 * 6144, 1024L * 6144, 1, 6144,
                                           Tt, se, (long)PLANE,
                                           Rre, Rim, (long)PLANE, 1024,
                                           1536, 2, 1.0f, 0, Phorner);
        reduce_k<<<gr, blk, 0, stream>>>(Rre, Phorner, 1.0f / (float)j, 1);
        float* t;
        t = Tre; Tre = Rre; Rre = t;
        t = Tim; Tim = Rim; Rim = t;
    }
    // 9 squarings: T <- T @ T
    for (int s = 0; s < 9; ++s) {
        pack_A6_k<<<dim3(2048), blk, 0, stream>>>(Tre, Tim, At);
        pack_BT6_k<<<dim3(16, 16, 2), blk, 0, stream>>>(Tre, Tim, Tt);
        gemm256_k<<<ge, blk5, 0, stream>>>(At, 2L * 1024 * 6144, 1024L * 6144, 1, 6144,
                                           Tt, se, (long)PLANE,
                                           Rre, Rim, (long)PLANE, 1024,
                                           1536, 2, 1.0f, 0, Psquare);
        reduce_k<<<gr, blk, 0, stream>>>(Rre, Psquare, 1.0f, 0);
        float* t;
        t = Tre; Tre = Rre; Rre = t;
        t = Tim; Tim = Rim; Rim = t;
    }

    // Apply: out[k,b1] = U[k] @ X[k,b1]
    pack_A4_k<<<dim3(2048), blk, 0, stream>>>(Tre, Tim, Aap);
    pack_xT_k<<<dim3(64, 16, 4), blk, 0, stream>>>(x_re, x_im, xT);

    SegOff sa;
    sa.o[0] = 0L;        sa.o[1] = 0L;
    sa.o[2] = 4L << 22;  sa.o[3] = 4L << 22;
    sa.o[4] = 0L;        sa.o[5] = 0L;

    gemm256_k<<<dim3(16, 4, 8), blk5, 0, stream>>>(Aap, 2L * 1024 * 4096, 1024L * 4096, 2, 4096,
                                                   xT, sa, 1L << 22,
                                                   out, out + (1L << 24), 1L << 22, 4096,
                                                   4096, 4, 1.0f, 0, (float*)nullptr);
}

// Round 5
// 1964.744 us; speedup vs baseline: 1.4327x; 1.0621x over previous
//
#include <hip/hip_runtime.h>
#include <hip/hip_bf16.h>

#define PLANE (1 << 20)   // 1024*1024

typedef __attribute__((ext_vector_type(8))) short bf16x8;
typedef __attribute__((ext_vector_type(4))) float f32x4;

struct SegOff { long o[6]; };

union U4 { ushort u[4]; unsigned long long v; };

__device__ __forceinline__ ushort bf16bits(float v) {
    union { __hip_bfloat16 b; ushort u; } c;
    c.b = __float2bfloat16(v);
    return c.u;
}

__device__ __forceinline__ void split2(float v, ushort& hi, ushort& lo) {
    union { __hip_bfloat16 b; ushort u; } c;
    __hip_bfloat16 h = __float2bfloat16(v);
    c.b = h; hi = c.u;
    c.b = __float2bfloat16(v - __bfloat162float(h));
    lo = c.u;
}

__device__ __forceinline__ void gload16(const ushort* g, ushort* l) {
    __builtin_amdgcn_global_load_lds(
        (const __attribute__((address_space(1))) unsigned int*)g,
        (__attribute__((address_space(3))) unsigned int*)l, 16, 0, 0);
}

// ---------------------------------------------------------------------------
// B = (A - A^H) * scale
// ---------------------------------------------------------------------------
__global__ __launch_bounds__(256) void build_skew_k(
    const float* __restrict__ Ure, const float* __restrict__ Uim,
    float* __restrict__ Bre, float* __restrict__ Bim, float scale)
{
    int idx = blockIdx.x * 256 + threadIdx.x;
    int ij  = idx & (PLANE - 1);
    int i   = ij >> 10, j = ij & 1023;
    int t   = (idx & ~(PLANE - 1)) | (j << 10) | i;
    Bre[idx] = (Ure[idx] - Ure[t]) * scale;
    Bim[idx] = (Uim[idx] + Uim[t]) * scale;
}

// T = I + B * inv
__global__ __launch_bounds__(256) void init_T_k(
    const float* __restrict__ Bre, const float* __restrict__ Bim,
    float* __restrict__ Tre, float* __restrict__ Tim, float inv)
{
    int idx = blockIdx.x * 256 + threadIdx.x;
    int ij  = idx & (PLANE - 1);
    int i   = ij >> 10, j = ij & 1023;
    Tre[idx] = Bre[idx] * inv + ((i == j) ? 1.0f : 0.0f);
    Tim[idx] = Bim[idx] * inv;
}

// ---------------------------------------------------------------------------
// Split-K reduction: C = (C + P0 + P1 + P2) * scale  [+ I on real diagonal]
// ---------------------------------------------------------------------------
__global__ __launch_bounds__(256) void reduce_k(
    float* __restrict__ C, const float* __restrict__ PB, float scale, int addI)
{
    long e = ((long)blockIdx.x * 256 + threadIdx.x) * 4;   // 4*PLANE floats total
    float4 v = *(float4*)(C + e);
    const float4 a = *(const float4*)(PB + e);
    const float4 b = *(const float4*)(PB + 4L * PLANE + e);
    const float4 c = *(const float4*)(PB + 8L * PLANE + e);
    v.x = (v.x + a.x + b.x + c.x) * scale;
    v.y = (v.y + a.y + b.y + c.y) * scale;
    v.z = (v.z + a.z + b.z + c.z) * scale;
    v.w = (v.w + a.w + b.w + c.w) * scale;
    if (addI) {
        long p = e >> 20;                 // plane index 0..3 (0,1 = real part)
        if (p < 2) {
            int ij = (int)(e & (PLANE - 1));
            int i = ij >> 10, j = ij & 1023;
            if (i >= j && i < j + 4) ((float*)&v)[i - j] += 1.0f;
        }
    }
    *(float4*)(C + e) = v;
}

// ---------------------------------------------------------------------------
// Pack A (expm, 6 segments): Ab[4 z][1024][6144]
// ---------------------------------------------------------------------------
__global__ __launch_bounds__(256) void pack_A6_k(
    const float* __restrict__ Sre, const float* __restrict__ Sim,
    ushort* __restrict__ Ab)
{
    int idx = blockIdx.x * 256 + threadIdx.x;     // 524288 threads
    int k   = idx >> 18;
    int m   = (idx >> 8) & 1023;
    int c4  = (idx & 255) * 4;
    const float4 vr = *(const float4*)(Sre + (size_t)k * PLANE + (size_t)m * 1024 + c4);
    const float4 vi = *(const float4*)(Sim + (size_t)k * PLANE + (size_t)m * 1024 + c4);
    U4 rh, rl, ih, il, nih, nil;
    split2(vr.x, rh.u[0], rl.u[0]); split2(vr.y, rh.u[1], rl.u[1]);
    split2(vr.z, rh.u[2], rl.u[2]); split2(vr.w, rh.u[3], rl.u[3]);
    split2(vi.x, ih.u[0], il.u[0]); split2(vi.y, ih.u[1], il.u[1]);
    split2(vi.z, ih.u[2], il.u[2]); split2(vi.w, ih.u[3], il.u[3]);
    #pragma unroll
    for (int i = 0; i < 4; ++i) { nih.u[i] = ih.u[i] ^ 0x8000; nil.u[i] = il.u[i] ^ 0x8000; }

    long b0 = (long)k * 1024 * 6144 + (long)m * 6144;
    long b1 = (long)(2 + k) * 1024 * 6144 + (long)m * 6144;
    *(unsigned long long*)&Ab[b0 + 0*1024 + c4] = rh.v;
    *(unsigned long long*)&Ab[b0 + 1*1024 + c4] = rh.v;
    *(unsigned long long*)&Ab[b0 + 2*1024 + c4] = rl.v;
    *(unsigned long long*)&Ab[b0 + 3*1024 + c4] = nih.v;
    *(unsigned long long*)&Ab[b0 + 4*1024 + c4] = nih.v;
    *(unsigned long long*)&Ab[b0 + 5*1024 + c4] = nil.v;
    *(unsigned long long*)&Ab[b1 + 0*1024 + c4] = ih.v;
    *(unsigned long long*)&Ab[b1 + 1*1024 + c4] = ih.v;
    *(unsigned long long*)&Ab[b1 + 2*1024 + c4] = il.v;
    *(unsigned long long*)&Ab[b1 + 3*1024 + c4] = rh.v;
    *(unsigned long long*)&Ab[b1 + 4*1024 + c4] = rh.v;
    *(unsigned long long*)&Ab[b1 + 5*1024 + c4] = rl.v;
}

// ---------------------------------------------------------------------------
// Pack A (apply, 4 segments): Ab[4 z][1024][4096]
// ---------------------------------------------------------------------------
__global__ __launch_bounds__(256) void pack_A4_k(
    const float* __restrict__ Sre, const float* __restrict__ Sim,
    ushort* __restrict__ Ab)
{
    int idx = blockIdx.x * 256 + threadIdx.x;
    int k   = idx >> 18;
    int m   = (idx >> 8) & 1023;
    int c4  = (idx & 255) * 4;
    const float4 vr = *(const float4*)(Sre + (size_t)k * PLANE + (size_t)m * 1024 + c4);
    const float4 vi = *(const float4*)(Sim + (size_t)k * PLANE + (size_t)m * 1024 + c4);
    U4 rh, rl, ih, il, nih, nil;
    split2(vr.x, rh.u[0], rl.u[0]); split2(vr.y, rh.u[1], rl.u[1]);
    split2(vr.z, rh.u[2], rl.u[2]); split2(vr.w, rh.u[3], rl.u[3]);
    split2(vi.x, ih.u[0], il.u[0]); split2(vi.y, ih.u[1], il.u[1]);
    split2(vi.z, ih.u[2], il.u[2]); split2(vi.w, ih.u[3], il.u[3]);
    #pragma unroll
    for (int i = 0; i < 4; ++i) { nih.u[i] = ih.u[i] ^ 0x8000; nil.u[i] = il.u[i] ^ 0x8000; }

    long b0 = (long)k * 1024 * 4096 + (long)m * 4096;
    long b1 = (long)(2 + k) * 1024 * 4096 + (long)m * 4096;
    *(unsigned long long*)&Ab[b0 + 0*1024 + c4] = rh.v;
    *(unsigned long long*)&Ab[b0 + 1*1024 + c4] = rl.v;
    *(unsigned long long*)&Ab[b0 + 2*1024 + c4] = nih.v;
    *(unsigned long long*)&Ab[b0 + 3*1024 + c4] = nil.v;
    *(unsigned long long*)&Ab[b1 + 0*1024 + c4] = ih.v;
    *(unsigned long long*)&Ab[b1 + 1*1024 + c4] = il.v;
    *(unsigned long long*)&Ab[b1 + 2*1024 + c4] = rh.v;
    *(unsigned long long*)&Ab[b1 + 3*1024 + c4] = rl.v;
}

// ---------------------------------------------------------------------------
// Transpose + split T -> Tt[4 kind][2 k][1024][1024]  (kind: rh, rl, ih, il)
// ---------------------------------------------------------------------------
__global__ __launch_bounds__(256) void pack_BT6_k(
    const float* __restrict__ Sre, const float* __restrict__ Sim,
    ushort* __restrict__ Tt)
{
    __shared__ float Lre[64][65];
    __shared__ float Lim[64][65];
    int k = blockIdx.z, r0 = blockIdx.y * 64, c0 = blockIdx.x * 64;
    int tid = threadIdx.x;
    const float* br = Sre + (size_t)k * PLANE;
    const float* bi = Sim + (size_t)k * PLANE;
    #pragma unroll
    for (int p = 0; p < 16; ++p) {
        int idx = p * 256 + tid, r = idx >> 6, c = idx & 63;
        Lre[r][c] = br[(size_t)(r0 + r) * 1024 + c0 + c];
        Lim[r][c] = bi[(size_t)(r0 + r) * 1024 + c0 + c];
    }
    __syncthreads();
    #pragma unroll
    for (int p = 0; p < 4; ++p) {
        int s = p * 256 + tid, oc = s >> 4, r4 = (s & 15) * 4;
        U4 rh, rl, ih, il;
        #pragma unroll
        for (int i = 0; i < 4; ++i) {
            split2(Lre[r4 + i][oc], rh.u[i], rl.u[i]);
            split2(Lim[r4 + i][oc], ih.u[i], il.u[i]);
        }
        size_t dst = (size_t)k * PLANE + (size_t)(c0 + oc) * 1024 + r0 + r4;
        *(unsigned long long*)&Tt[0L * 2 * PLANE + dst] = rh.v;
        *(unsigned long long*)&Tt[1L * 2 * PLANE + dst] = rl.v;
        *(unsigned long long*)&Tt[2L * 2 * PLANE + dst] = ih.v;
        *(unsigned long long*)&Tt[3L * 2 * PLANE + dst] = il.v;
    }
}

// ---------------------------------------------------------------------------
// Transpose + convert x -> xT[2 kind][4 plane][4096][1024] (plain bf16)
// ---------------------------------------------------------------------------
__global__ __launch_bounds__(256) void pack_xT_k(
    const float* __restrict__ xre, const float* __restrict__ xim,
    ushort* __restrict__ xT)
{
    __shared__ float Lre[64][65];
    __shared__ float Lim[64][65];
    int pl = blockIdx.z, t0 = blockIdx.y * 64, c0 = blockIdx.x * 64;
    int tid = threadIdx.x;
    const float* br = xre + ((size_t)pl << 22);
    const float* bi = xim + ((size_t)pl << 22);
    #pragma unroll
    for (int p = 0; p < 16; ++p) {
        int idx = p * 256 + tid, r = idx >> 6, c = idx & 63;
        Lre[r][c] = br[(size_t)(t0 + r) * 4096 + c0 + c];
        Lim[r][c] = bi[(size_t)(t0 + r) * 4096 + c0 + c];
    }
    __syncthreads();
    #pragma unroll
    for (int p = 0; p < 4; ++p) {
        int s = p * 256 + tid, oc = s >> 4, r4 = (s & 15) * 4;
        U4 re4, im4;
        #pragma unroll
        for (int i = 0; i < 4; ++i) {
            re4.u[i] = bf16bits(Lre[r4 + i][oc]);
            im4.u[i] = bf16bits(Lim[r4 + i][oc]);
        }
        size_t dst = ((size_t)pl << 22) + (size_t)(c0 + oc) * 1024 + t0 + r4;
        *(unsigned long long*)&xT[dst] = re4.v;
        *(unsigned long long*)&xT[(4L << 22) + dst] = im4.v;
    }
}

// ---------------------------------------------------------------------------
// 256x256-tile bf16 MFMA GEMM, per-phase interleaved schedule (m201-style).
// 512 threads = 8 waves (2M x 4N), per-wave output 128x64, BK=64.
// LDS 128 KiB = 2 dbuf x [A-K0|A-K1|B-K0|B-K1], each plane [256 rows][32 el]
// (64-B rows, 16 KB, contiguous so one half-tile = 2 gload16/thread).
// Swizzle: 16-B slot index = quad ^ (row & 3) within each 64-B row ->
// a wave's frag read (16 rows x 4 quads) tiles 1024 B bijectively =
// conflict-free; inverse applied to the per-lane GLOBAL source chunk
// (global_load_lds dest stays linear). All read offsets additive.
// Per tile: 4 phases, each {ds_read quadrant frags; stage ONE half-tile of
// tile t+1 into buf^1; barrier; setprio(1) 16 MFMA setprio(0); barrier}.
// -> LDS pipe (phase p+1 reads) overlaps matrix pipe (phase p MFMAs).
// vmcnt(4) twice per tile (end ph2, end ph4): outstanding always 8; each
// retires exactly the half-tiles the next two phases read; sealed by the
// following barrier. Never drains to 0. Tail tile re-stages itself into the
// dead buffer to keep the ledger uniform.
// ---------------------------------------------------------------------------
__global__ __launch_bounds__(512, 2) void gemm256_k(
    const ushort* __restrict__ Ab, long aPackStride, long aInnerStride, int aInnerDiv, int aLd,
    const ushort* __restrict__ Bb, SegOff segs, long bZStride,
    float* __restrict__ CreB, float* __restrict__ CimB, long cZStride, int cLd,
    int kLen, int zHalf, float scale, int addI,
    float* __restrict__ PB)
{
    __shared__ ushort lds[2][32768];   // [A-K0 8192 | A-K1 8192 | B-K0 8192 | B-K1 8192]

    const int zTot  = 2 * zHalf;
    const int chunk = blockIdx.z / zTot;
    const int zb    = blockIdx.z % zTot;
    const int pack  = zb / zHalf, inner = zb % zHalf;
    const ushort* A = Ab + (long)pack * aPackStride + (long)(inner / aInnerDiv) * aInnerStride;
    float* C = (chunk == 0)
        ? ((pack ? CimB : CreB) + (long)inner * cZStride)
        : (PB + (long)(chunk - 1) * 4 * PLANE + (long)pack * 2 * PLANE + (long)inner * PLANE);

    const int tid  = threadIdx.x;
    const int lane = tid & 63, wave = tid >> 6;
    const int wr = wave >> 2, wc = wave & 3;       // 2M x 4N wave grid
    const int l15 = lane & 15, quad = lane >> 4;
    const int m0 = blockIdx.y * 256, n0 = blockIdx.x * 256;

    // staging constants: linear LDS dest (L*512+tid)*16B; inverse-swz source
    const int r0s  = tid >> 2;                       // row for load L=0 (0..127)
    const int r1s  = 128 + r0s;                      // row for load L=1
    const int scol = ((tid & 3) ^ ((tid >> 2) & 3)) * 8;  // src element col in K-half
    const int dU0  = tid * 8;                        // dest ushort offset, L=0
    const int dU1  = 4096 + tid * 8;                 // dest ushort offset, L=1
    // fragment-read bases (ushort units), swizzle additive per thread
    const int swzE  = (quad * 8) ^ ((l15 & 3) << 3);
    const int aBase = wr * 4096 + l15 * 32 + swzE;   // + KQ*8192 + fm*512
    const int bBase = wc * 2048 + l15 * 32 + swzE;   // + 16384 + KQ*8192 + j*512

    const int kStart = chunk * kLen;
    const int nt = kLen >> 6;

    f32x4 acc[8][4] = {};

#define STAGE_A(KQ, T, BUF)                                                    \
    {                                                                          \
        int kb_ = kStart + (T) * 64;                                           \
        const ushort* g_ = A + kb_ + (KQ) * 32 + scol;                         \
        ushort* d_ = &lds[BUF][(KQ) * 8192];                                   \
        gload16(g_ + (long)(m0 + r0s) * aLd, d_ + dU0);                        \
        gload16(g_ + (long)(m0 + r1s) * aLd, d_ + dU1);                        \
    }
#define STAGE_B(KQ, T, BUF)                                                    \
    {                                                                          \
        int kb_ = kStart + (T) * 64;                                           \
        const ushort* g_ = Bb + segs.o[kb_ >> 10] + (long)inner * bZStride     \
                           + (kb_ & 1023) + (KQ) * 32 + scol;                  \
        ushort* d_ = &lds[BUF][16384 + (KQ) * 8192];                           \
        gload16(g_ + (long)(n0 + r0s) * 1024, d_ + dU0);                       \
        gload16(g_ + (long)(n0 + r1s) * 1024, d_ + dU1);                       \
    }

#define PHASE(MQ, KQ, LOADB, STAGE_STMT, VMFENCE)                              \
    {                                                                          \
        if (LOADB) {                                                           \
            _Pragma("unroll")                                                  \
            for (int j_ = 0; j_ < 4; ++j_)                                     \
                bfr[j_] = *(const bf16x8*)&lB[(KQ) * 8192 + bBase + j_ * 512]; \
        }                                                                      \
        bf16x8 aa[4];                                                          \
        _Pragma("unroll")                                                      \
        for (int i_ = 0; i_ < 4; ++i_)                                         \
            aa[i_] = *(const bf16x8*)&lA[(KQ) * 8192 + aBase + ((MQ) * 4 + i_) * 512]; \
        STAGE_STMT;                                                            \
        asm volatile("s_barrier" ::: "memory");                                \
        __builtin_amdgcn_s_setprio(1);                                         \
        _Pragma("unroll")                                                      \
        for (int i_ = 0; i_ < 4; ++i_) {                                       \
            _Pragma("unroll")                                                  \
            for (int j_ = 0; j_ < 4; ++j_)                                     \
                acc[(MQ) * 4 + i_][j_] = __builtin_amdgcn_mfma_f32_16x16x32_bf16( \
                    aa[i_], bfr[j_], acc[(MQ) * 4 + i_][j_], 0, 0, 0);         \
        }                                                                      \
        __builtin_amdgcn_s_setprio(0);                                         \
        VMFENCE;                                                               \
        asm volatile("s_barrier" ::: "memory");                                \
    }

    // prologue: all 4 half-tiles of tile 0; retire K0 halves, keep K1 in flight
    STAGE_A(0, 0, 0); STAGE_B(0, 0, 0); STAGE_A(1, 0, 0); STAGE_B(1, 0, 0);
    asm volatile("s_waitcnt vmcnt(4)" ::: "memory");
    asm volatile("s_barrier" ::: "memory");

    for (int t = 0; t < nt; ++t) {
        const int cur = t & 1, nx = cur ^ 1;
        const ushort* lA = &lds[cur][0];
        const ushort* lB = &lds[cur][16384];
        const int tn = (t + 1 < nt) ? (t + 1) : (nt - 1);  // tail: dead-buffer re-stage
        bf16x8 bfr[4];
        PHASE(0, 0, 1, STAGE_A(0, tn, nx), );
        PHASE(1, 0, 0, STAGE_B(0, tn, nx),
              asm volatile("s_waitcnt vmcnt(4)" ::: "memory"));
        PHASE(0, 1, 1, STAGE_A(1, tn, nx), );
        PHASE(1, 1, 0, STAGE_B(1, tn, nx),
              asm volatile("s_waitcnt vmcnt(4)" ::: "memory"));
    }
#undef PHASE
#undef STAGE_A
#undef STAGE_B

    #pragma unroll
    for (int fm = 0; fm < 8; ++fm) {
        int row0 = m0 + wr * 128 + fm * 16 + quad * 4;
        #pragma unroll
        for (int fn = 0; fn < 4; ++fn) {
            int col = n0 + wc * 64 + fn * 16 + l15;
            #pragma unroll
            for (int r = 0; r < 4; ++r) {
                float v = acc[fm][fn][r] * scale;
                if (addI && chunk == 0 && pack == 0 && (row0 + r) == col) v += 1.0f;
                C[(long)(row0 + r) * cLd + col] = v;
            }
        }
    }
}

// ---------------------------------------------------------------------------
extern "C" void kernel_launch(void* const* d_in, const int* in_sizes, int n_in,
                              void* d_out, int out_size, void* d_ws, size_t ws_size,
                              hipStream_t stream)
{
    const float* x_re = (const float*)d_in[0];
    const float* x_im = (const float*)d_in[1];
    const float* U_re = (const float*)d_in[2];
    const float* U_im = (const float*)d_in[3];
    float* out = (float*)d_out;

    // ws layout (160 MiB):
    //   [0,48M):   6 fp32 planes [2][1024][1024]: Tre,Tim,Rre,Rim,BSre,BSim
    //   [48,96M):  Askew bf16 [4][1024][6144]  (later reused as A_apply [4][1024][4096])
    //              -> during SQUARINGS this region is dead: split-K partials live here
    //   [96,144M): At bf16 [4][1024][6144]   } reused as xT [2][4][4096][1024] (64 MiB)
    //              -> during HORNER this region is dead: split-K partials live here
    //   [144,160M): Tt bf16 [4][2][1024][1024]
    float* fp = (float*)d_ws;
    float* Tre = fp + 0L * 2 * PLANE;
    float* Tim = fp + 1L * 2 * PLANE;
    float* Rre = fp + 2L * 2 * PLANE;
    float* Rim = fp + 3L * 2 * PLANE;
    float* BSre = fp + 4L * 2 * PLANE;
    float* BSim = fp + 5L * 2 * PLANE;
    ushort* Askew = (ushort*)((char*)d_ws + (48L << 20));
    ushort* At    = (ushort*)((char*)d_ws + (96L << 20));
    ushort* Tt    = (ushort*)((char*)d_ws + (144L << 20));
    ushort* Aap   = Askew;
    ushort* xT    = At;
    float* Phorner = (float*)At;      // 48 MiB free during Horner
    float* Psquare = (float*)Askew;   // 48 MiB free during squarings

    dim3 blk(256);
    dim3 blk5(512);

    const float scaleB = 1.0f / 512.0f;   // ||skew|| ~128 -> ||B|| ~0.25, s=9
    build_skew_k<<<dim3(2 * PLANE / 256), blk, 0, stream>>>(U_re, U_im, BSre, BSim, scaleB);
    init_T_k<<<dim3(2 * PLANE / 256), blk, 0, stream>>>(BSre, BSim, Tre, Tim, 1.0f / 8.0f);
    pack_A6_k<<<dim3(2048), blk, 0, stream>>>(BSre, BSim, Askew);

    SegOff se;
    se.o[0] = 0L;           se.o[1] = 2L * PLANE;  se.o[2] = 0L;
    se.o[3] = 4L * PLANE;   se.o[4] = 6L * PLANE;  se.o[5] = 4L * PLANE;

    dim3 ge(4, 4, 16);                 // 4x4 xy tiles, 4 z * 4 K-chunks = 256 blocks (1/CU)
    dim3 gr(PLANE / 256);              // reduce: 4*PLANE floats / (256*4)
    // Horner: T <- I + (B @ T)/j
    for (int j = 7; j >= 1; --j) {
        pack_BT6_k<<<dim3(16, 16, 2), blk, 0, stream>>>(Tre, Tim, Tt);
        gemm256_k<<<ge, blk5, 0, stream>>>(Askew, 2L * 1024 * 6144, 1024L * 6144, 1, 6144,
                                           Tt, se, (long)PLANE,
                                           Rre, Rim, (long)PLANE, 1024,
                                           1536, 2, 1.0f, 0, Phorner);
        reduce_k<<<gr, blk, 0, stream>>>(Rre, Phorner, 1.0f / (float)j, 1);
        float* t;
        t = Tre; Tre = Rre; Rre = t;
        t = Tim; Tim = Rim; Rim = t;
    }
    // 9 squarings: T <- T @ T
    for (int s = 0; s < 9; ++s) {
        pack_A6_k<<<dim3(2048), blk, 0, stream>>>(Tre, Tim, At);
        pack_BT6_k<<<dim3(16, 16, 2), blk, 0, stream>>>(Tre, Tim, Tt);
        gemm256_k<<<ge, blk5, 0, stream>>>(At, 2L * 1024 * 6144, 1024L * 6144, 1, 6144,
                                           Tt, se, (long)PLANE,
                                           Rre, Rim, (long)PLANE, 1024,
                                           1536, 2, 1.0f, 0, Psquare);
        reduce_k<<<gr, blk, 0, stream>>>(Rre, Psquare, 1.0f, 0);
        float* t;
        t = Tre; Tre = Rre; Rre = t;
        t = Tim; Tim = Rim; Rim = t;
    }

    // Apply: out[k,b1] = U[k] @ X[k,b1]
    pack_A4_k<<<dim3(2048), blk, 0, stream>>>(Tre, Tim, Aap);
    pack_xT_k<<<dim3(64, 16, 4), blk, 0, stream>>>(x_re, x_im, xT);

    SegOff sa;
    sa.o[0] = 0L;        sa.o[1] = 0L;
    sa.o[2] = 4L << 22;  sa.o[3] = 4L << 22;
    sa.o[4] = 0L;        sa.o[5] = 0L;

    gemm256_k<<<dim3(16, 4, 8), blk5, 0, stream>>>(Aap, 2L * 1024 * 4096, 1024L * 4096, 2, 4096,
                                                   xT, sa, 1L << 22,
                                                   out, out + (1L << 24), 1L << 22, 4096,
                                                   4096, 4, 1.0f, 0, (float*)nullptr);
}